// Round 2
// baseline (1317.039 us; speedup 1.0000x reference)
//
#include <hip/hip_runtime.h>
#include <hip/hip_bf16.h>
#include <math.h>

// ---------------------------------------------------------------------------
// GAT (3x GATConv, PyG-style) on MI355X. Round 1: fp32 compute, bf16 storage
// for the two big activation buffers (workspace-overflow fix), ws_size guard.
// Pipeline per layer: sgemm (h = x@W) -> alpha dots -> CSR softmax -> aggregate.
// CSR over dst built on-device per call (no float atomics anywhere).
// ---------------------------------------------------------------------------

#define LEAKY_SLOPE 0.2f

typedef __hip_bfloat16 bf16;

__device__ __forceinline__ float tof(float x) { return x; }
__device__ __forceinline__ float tof(bf16 x) { return __bfloat162float(x); }

__device__ __forceinline__ int edge_val(const int* __restrict__ ei, int is64, long long idx) {
    return is64 ? ei[2 * idx] : ei[idx];
}

// Detect whether edge_index is int64 (little-endian: odd 4-byte words are 0).
__global__ void detect_kernel(const unsigned int* __restrict__ ei, int* __restrict__ flag) {
    if (threadIdx.x == 0 && blockIdx.x == 0) {
        int is64 = 1;
        for (int i = 0; i < 64; ++i)
            if (ei[2 * i + 1] != 0u) { is64 = 0; break; }
        *flag = is64;
    }
}

__global__ __launch_bounds__(256) void zero2_kernel(int* __restrict__ a, int* __restrict__ b, int n) {
    int i = blockIdx.x * blockDim.x + threadIdx.x;
    if (i < n) { a[i] = 0; b[i] = 0; }
}

__global__ __launch_bounds__(256) void sentinel_kernel(float* __restrict__ out, int n, float v) {
    int i = blockIdx.x * blockDim.x + threadIdx.x;
    if (i < n) out[i] = v;
}

__global__ __launch_bounds__(256) void count_kernel(const int* __restrict__ ei,
                                                    const int* __restrict__ flag,
                                                    int E, int N, int* __restrict__ counts) {
    int e = blockIdx.x * blockDim.x + threadIdx.x;
    if (e >= E + N) return;
    int is64 = *flag;
    int d = (e < E) ? edge_val(ei, is64, (long long)E + e) : (e - E);
    atomicAdd(&counts[d], 1);
}

// Single-block exclusive scan of counts[N] -> ptr[N+1].
__global__ __launch_bounds__(1024) void scan_kernel(const int* __restrict__ counts,
                                                    int* __restrict__ ptrArr, int N) {
    __shared__ int sums[1024];
    int tid = threadIdx.x;
    int chunk = (N + 1023) / 1024;
    int b = tid * chunk;
    int e = b + chunk; if (e > N) e = N; if (b > N) b = N;
    int s = 0;
    for (int i = b; i < e; ++i) s += counts[i];
    sums[tid] = s;
    __syncthreads();
    for (int off = 1; off < 1024; off <<= 1) {
        int v = (tid >= off) ? sums[tid - off] : 0;
        __syncthreads();
        sums[tid] += v;
        __syncthreads();
    }
    int run = (tid == 0) ? 0 : sums[tid - 1];
    for (int i = b; i < e; ++i) { ptrArr[i] = run; run += counts[i]; }
    if (tid == 1023) ptrArr[N] = sums[1023];
}

__global__ __launch_bounds__(256) void fill_kernel(const int* __restrict__ ei,
                                                   const int* __restrict__ flag,
                                                   int E, int N,
                                                   const int* __restrict__ ptrArr,
                                                   int* __restrict__ cursor,
                                                   int* __restrict__ csr_src) {
    int e = blockIdx.x * blockDim.x + threadIdx.x;
    if (e >= E + N) return;
    int is64 = *flag;
    int s, d;
    if (e < E) {
        s = edge_val(ei, is64, e);
        d = edge_val(ei, is64, (long long)E + e);
    } else {
        s = d = e - E;
    }
    int slot = atomicAdd(&cursor[d], 1);
    csr_src[ptrArr[d] + slot] = s;
}

// ---------------------------------------------------------------------------
// Tiled GEMM: C[M,N] = A[M,K] @ B[K,N]. BM=BN=64, BK=16, 256 thr, 4x4/thr.
// A is fp32 or bf16 (template); B fp32; C bf16. K%16==0, N%64==0 hold.
// ---------------------------------------------------------------------------
template <typename TA>
__global__ __launch_bounds__(256) void sgemm_kernel(const TA* __restrict__ A,
                                                    const float* __restrict__ B,
                                                    bf16* __restrict__ C,
                                                    int M, int K, int N) {
    __shared__ float As[16][68];
    __shared__ float Bs[16][68];
    int bm = blockIdx.y * 64;
    int bn = blockIdx.x * 64;
    int tid = threadIdx.x;
    int tx = tid & 15, ty = tid >> 4;
    int tx4 = tx * 4, ty4 = ty * 4;
    float acc[4][4];
#pragma unroll
    for (int i = 0; i < 4; ++i)
#pragma unroll
        for (int j = 0; j < 4; ++j) acc[i][j] = 0.f;

    for (int k0 = 0; k0 < K; k0 += 16) {
#pragma unroll
        for (int it = 0; it < 4; ++it) {
            int idx = tid + it * 256;
            int r = idx >> 4, kk = idx & 15;
            int row = bm + r;
            float v = 0.f;
            if (row < M) v = tof(A[(size_t)row * K + k0 + kk]);
            As[kk][r] = v;
        }
#pragma unroll
        for (int it = 0; it < 4; ++it) {
            int idx = tid + it * 256;
            int kk = idx >> 6, c = idx & 63;
            Bs[kk][c] = B[(size_t)(k0 + kk) * N + bn + c];
        }
        __syncthreads();
#pragma unroll
        for (int kk = 0; kk < 16; ++kk) {
            float a4[4], b4[4];
#pragma unroll
            for (int i = 0; i < 4; ++i) a4[i] = As[kk][ty4 + i];
#pragma unroll
            for (int j = 0; j < 4; ++j) b4[j] = Bs[kk][tx4 + j];
#pragma unroll
            for (int i = 0; i < 4; ++i)
#pragma unroll
                for (int j = 0; j < 4; ++j)
                    acc[i][j] = fmaf(a4[i], b4[j], acc[i][j]);
        }
        __syncthreads();
    }
#pragma unroll
    for (int i = 0; i < 4; ++i) {
        int row = bm + ty4 + i;
        if (row < M) {
#pragma unroll
            for (int j = 0; j < 4; ++j)
                C[(size_t)row * N + bn + tx4 + j] = __float2bfloat16(acc[i][j]);
        }
    }
}

// ---------------------------------------------------------------------------
// alpha_s[n,h] = sum_c h[n,h,c]*a_src[h,c] ; same for alpha_d. One wave/node.
// ---------------------------------------------------------------------------
template <int H, int C>
__global__ __launch_bounds__(256) void alpha_kernel(const bf16* __restrict__ h,
                                                    const float* __restrict__ a_s,
                                                    const float* __restrict__ a_d,
                                                    float* __restrict__ out_s,
                                                    float* __restrict__ out_d, int N) {
    int lane = threadIdx.x & 63;
    int wid = threadIdx.x >> 6;
    int n = blockIdx.x * (blockDim.x >> 6) + wid;
    if (n >= N) return;
    const bf16* hrow = h + (size_t)n * H * C;
#pragma unroll
    for (int hh = 0; hh < H; ++hh) {
        float ps = 0.f, pd = 0.f;
        for (int c = lane; c < C; c += 64) {
            float v = tof(hrow[hh * C + c]);
            ps += v * a_s[hh * C + c];
            pd += v * a_d[hh * C + c];
        }
#pragma unroll
        for (int off = 32; off; off >>= 1) {
            ps += __shfl_xor(ps, off);
            pd += __shfl_xor(pd, off);
        }
        if (lane == 0) {
            out_s[(size_t)n * H + hh] = ps;
            out_d[(size_t)n * H + hh] = pd;
        }
    }
}

// ---------------------------------------------------------------------------
// Segment softmax per dst node (CSR). One wave per node; recompute e per pass.
// ---------------------------------------------------------------------------
template <int H>
__global__ __launch_bounds__(256) void softmax_kernel(const int* __restrict__ ptrArr,
                                                      const int* __restrict__ csr_src,
                                                      const float* __restrict__ as,
                                                      const float* __restrict__ ad,
                                                      float* __restrict__ alpha_ws, int N) {
    int lane = threadIdx.x & 63;
    int wid = threadIdx.x >> 6;
    int n = blockIdx.x * (blockDim.x >> 6) + wid;
    if (n >= N) return;
    int beg = ptrArr[n], end = ptrArr[n + 1];
#pragma unroll
    for (int hh = 0; hh < H; ++hh) {
        float advv = ad[(size_t)n * H + hh];
        float m = -INFINITY;
        for (int i = beg + lane; i < end; i += 64) {
            int s = csr_src[i];
            float v = as[(size_t)s * H + hh] + advv;
            v = (v >= 0.f) ? v : LEAKY_SLOPE * v;
            m = fmaxf(m, v);
        }
#pragma unroll
        for (int off = 32; off; off >>= 1) m = fmaxf(m, __shfl_xor(m, off));
        float ssum = 0.f;
        for (int i = beg + lane; i < end; i += 64) {
            int s = csr_src[i];
            float v = as[(size_t)s * H + hh] + advv;
            v = (v >= 0.f) ? v : LEAKY_SLOPE * v;
            ssum += expf(v - m);
        }
#pragma unroll
        for (int off = 32; off; off >>= 1) ssum += __shfl_xor(ssum, off);
        float inv = 1.f / (ssum + 1e-16f);
        for (int i = beg + lane; i < end; i += 64) {
            int s = csr_src[i];
            float v = as[(size_t)s * H + hh] + advv;
            v = (v >= 0.f) ? v : LEAKY_SLOPE * v;
            alpha_ws[(size_t)i * H + hh] = expf(v - m) * inv;
        }
    }
}

// ---------------------------------------------------------------------------
// out[n,:] = sum_{e in in(n)} alpha_e * h[src_e,:] + b ; optional ELU.
// One wave per node; F/64 accumulators per lane. F in {512, 256}.
// ---------------------------------------------------------------------------
template <int H, int C, bool DO_ELU>
__global__ __launch_bounds__(256) void aggregate_kernel(const int* __restrict__ ptrArr,
                                                        const int* __restrict__ csr_src,
                                                        const float* __restrict__ alpha_ws,
                                                        const bf16* __restrict__ hmat,
                                                        const float* __restrict__ bias,
                                                        bf16* __restrict__ out, int N) {
    constexpr int F = H * C;
    constexpr int JPT = F / 64;
    int lane = threadIdx.x & 63;
    int wid = threadIdx.x >> 6;
    int n = blockIdx.x * (blockDim.x >> 6) + wid;
    if (n >= N) return;
    int beg = ptrArr[n], end = ptrArr[n + 1];
    float acc[JPT];
#pragma unroll
    for (int q = 0; q < JPT; ++q) acc[q] = 0.f;
    for (int i = beg; i < end; ++i) {
        int s = csr_src[i];
        const bf16* hrow = hmat + (size_t)s * F;
#pragma unroll
        for (int q = 0; q < JPT; ++q) {
            float al = alpha_ws[(size_t)i * H + (q * 64) / C];  // wave-uniform head idx
            acc[q] += al * tof(hrow[lane + q * 64]);
        }
    }
#pragma unroll
    for (int q = 0; q < JPT; ++q) {
        int j = lane + q * 64;
        float v = acc[q] + bias[j];
        if (DO_ELU) v = (v > 0.f) ? v : expm1f(v);
        out[(size_t)n * F + j] = __float2bfloat16(v);
    }
}

// ---------------------------------------------------------------------------
// Layer 3: h3 = x3 @ W3 (K=256, 2 cols) fused with alpha dots. One wave/node.
// ---------------------------------------------------------------------------
__global__ __launch_bounds__(256) void layer3_gemm_kernel(const bf16* __restrict__ x,
                                                          const float* __restrict__ W,
                                                          const float* __restrict__ a_s,
                                                          const float* __restrict__ a_d,
                                                          float* __restrict__ h3,
                                                          float* __restrict__ out_s,
                                                          float* __restrict__ out_d, int N) {
    int lane = threadIdx.x & 63;
    int wid = threadIdx.x >> 6;
    int n = blockIdx.x * (blockDim.x >> 6) + wid;
    if (n >= N) return;
    const bf16* xr = x + (size_t)n * 256;
    float a0 = 0.f, a1 = 0.f;
#pragma unroll
    for (int q = 0; q < 4; ++q) {
        int k = lane + q * 64;
        float v = tof(xr[k]);
        a0 += v * W[k * 2 + 0];
        a1 += v * W[k * 2 + 1];
    }
#pragma unroll
    for (int off = 32; off; off >>= 1) {
        a0 += __shfl_xor(a0, off);
        a1 += __shfl_xor(a1, off);
    }
    if (lane == 0) {
        h3[(size_t)n * 2 + 0] = a0;
        h3[(size_t)n * 2 + 1] = a1;
        out_s[n] = a0 * a_s[0] + a1 * a_s[1];
        out_d[n] = a0 * a_d[0] + a1 * a_d[1];
    }
}

__global__ __launch_bounds__(256) void aggregate3_kernel(const int* __restrict__ ptrArr,
                                                         const int* __restrict__ csr_src,
                                                         const float* __restrict__ alpha_ws,
                                                         const float* __restrict__ h3,
                                                         const float* __restrict__ b3,
                                                         float* __restrict__ out, int N) {
    int n = blockIdx.x * blockDim.x + threadIdx.x;
    if (n >= N) return;
    float a0 = 0.f, a1 = 0.f;
    int beg = ptrArr[n], end = ptrArr[n + 1];
    for (int i = beg; i < end; ++i) {
        int s = csr_src[i];
        float al = alpha_ws[i];
        a0 += al * h3[(size_t)s * 2 + 0];
        a1 += al * h3[(size_t)s * 2 + 1];
    }
    out[(size_t)n * 2 + 0] = a0 + b3[0];
    out[(size_t)n * 2 + 1] = a1 + b3[1];
}

// ---------------------------------------------------------------------------

extern "C" void kernel_launch(void* const* d_in, const int* in_sizes, int n_in,
                              void* d_out, int out_size, void* d_ws, size_t ws_size,
                              hipStream_t stream) {
    const float* x      = (const float*)d_in[0];
    const int*   ei     = (const int*)d_in[1];
    const float* W1     = (const float*)d_in[2];
    const float* a_src1 = (const float*)d_in[3];
    const float* a_dst1 = (const float*)d_in[4];
    const float* b1     = (const float*)d_in[5];
    const float* W2     = (const float*)d_in[6];
    const float* a_src2 = (const float*)d_in[7];
    const float* a_dst2 = (const float*)d_in[8];
    const float* b2     = (const float*)d_in[9];
    const float* W3     = (const float*)d_in[10];
    const float* a_src3 = (const float*)d_in[11];
    const float* a_dst3 = (const float*)d_in[12];
    const float* b3     = (const float*)d_in[13];

    const int N = in_sizes[0] / 128;
    const int E = in_sizes[1] / 2;
    const int ET = E + N;  // with self-loops

    // ---- workspace carve (256B aligned), with explicit size guard ----
    size_t need = 0;
    auto carve = [&](size_t bytes) -> size_t {
        size_t off = need;
        need += (bytes + 255) & ~(size_t)255;
        return off;
    };
    size_t o_counts   = carve((size_t)N * 4);
    size_t o_cursor   = carve((size_t)N * 4);
    size_t o_ptr      = carve((size_t)(N + 1) * 4);
    size_t o_csr      = carve((size_t)ET * 4);
    size_t o_flag     = carve(4);
    size_t o_alpha_s  = carve((size_t)N * 4 * 4);
    size_t o_alpha_d  = carve((size_t)N * 4 * 4);
    size_t o_alpha_ws = carve((size_t)ET * 4 * 4);
    size_t o_h3       = carve((size_t)N * 2 * 4);
    size_t o_bufA     = carve((size_t)N * 512 * 2);  // bf16
    size_t o_bufB     = carve((size_t)N * 512 * 2);  // bf16

    if (need > ws_size) {
        // Workspace too small: report its MB count through the absmax error.
        sentinel_kernel<<<(out_size + 255) / 256, 256, 0, stream>>>(
            (float*)d_out, out_size, (float)(ws_size >> 20));
        return;
    }

    char* w = (char*)d_ws;
    int*   counts   = (int*)(w + o_counts);
    int*   cursor   = (int*)(w + o_cursor);
    int*   ptrArr   = (int*)(w + o_ptr);
    int*   csr_src  = (int*)(w + o_csr);
    int*   flag     = (int*)(w + o_flag);
    float* alpha_s  = (float*)(w + o_alpha_s);
    float* alpha_d  = (float*)(w + o_alpha_d);
    float* alpha_ws = (float*)(w + o_alpha_ws);
    float* h3       = (float*)(w + o_h3);
    bf16*  bufA     = (bf16*)(w + o_bufA);
    bf16*  bufB     = (bf16*)(w + o_bufB);

    const int edge_blocks = (ET + 255) / 256;
    const int node_wave_blocks = (N + 3) / 4;   // 4 waves per 256-thr block
    const int node_thr_blocks = (N + 255) / 256;

    // ---- CSR build (shared by all 3 layers) ----
    zero2_kernel<<<node_thr_blocks, 256, 0, stream>>>(counts, cursor, N);
    detect_kernel<<<1, 1, 0, stream>>>((const unsigned int*)ei, flag);
    count_kernel<<<edge_blocks, 256, 0, stream>>>(ei, flag, E, N, counts);
    scan_kernel<<<1, 1024, 0, stream>>>(counts, ptrArr, N);
    fill_kernel<<<edge_blocks, 256, 0, stream>>>(ei, flag, E, N, ptrArr, cursor, csr_src);

    // ---- Layer 1: 128 -> 4x128, concat, ELU ----
    {
        dim3 g(512 / 64, (N + 63) / 64);
        sgemm_kernel<float><<<g, 256, 0, stream>>>(x, W1, bufA, N, 128, 512);
        alpha_kernel<4, 128><<<node_wave_blocks, 256, 0, stream>>>(bufA, a_src1, a_dst1, alpha_s, alpha_d, N);
        softmax_kernel<4><<<node_wave_blocks, 256, 0, stream>>>(ptrArr, csr_src, alpha_s, alpha_d, alpha_ws, N);
        aggregate_kernel<4, 128, true><<<node_wave_blocks, 256, 0, stream>>>(ptrArr, csr_src, alpha_ws, bufA, b1, bufB, N);
    }
    // ---- Layer 2: 512 -> 4x64, concat, ELU ----
    {
        dim3 g(256 / 64, (N + 63) / 64);
        sgemm_kernel<bf16><<<g, 256, 0, stream>>>(bufB, W2, bufA, N, 512, 256);
        alpha_kernel<4, 64><<<node_wave_blocks, 256, 0, stream>>>(bufA, a_src2, a_dst2, alpha_s, alpha_d, N);
        softmax_kernel<4><<<node_wave_blocks, 256, 0, stream>>>(ptrArr, csr_src, alpha_s, alpha_d, alpha_ws, N);
        aggregate_kernel<4, 64, true><<<node_wave_blocks, 256, 0, stream>>>(ptrArr, csr_src, alpha_ws, bufA, b2, bufB, N);
    }
    // ---- Layer 3: 256 -> 2, heads=1, mean(=identity), no ELU ----
    {
        layer3_gemm_kernel<<<node_wave_blocks, 256, 0, stream>>>(bufB, W3, a_src3, a_dst3, h3, alpha_s, alpha_d, N);
        softmax_kernel<1><<<node_wave_blocks, 256, 0, stream>>>(ptrArr, csr_src, alpha_s, alpha_d, alpha_ws, N);
        aggregate3_kernel<<<node_thr_blocks, 256, 0, stream>>>(ptrArr, csr_src, alpha_ws, h3, b3, (float*)d_out, N);
    }
}

// Round 3
// 580.725 us; speedup vs baseline: 2.2679x; 2.2679x over previous
//
#include <hip/hip_runtime.h>
#include <hip/hip_bf16.h>
#include <math.h>

// ---------------------------------------------------------------------------
// GAT (3x GATConv, PyG-style) on MI355X. Round 2: MFMA bf16 GEMMs (XOR-swizzled
// LDS, 128x128x64 tiles), vectorized edge phase (16B/lane loads), blocked scan.
// CSR over dst built on-device per call (no float atomics anywhere).
// ---------------------------------------------------------------------------

#define LEAKY_SLOPE 0.2f

typedef __attribute__((ext_vector_type(8))) short bf16x8;
typedef __attribute__((ext_vector_type(4))) float f32x4;
typedef __attribute__((ext_vector_type(4))) float fx4;

__device__ __forceinline__ unsigned short f2bf(float f) {
    unsigned int x = __float_as_uint(f);
    x += 0x7fffu + ((x >> 16) & 1u);   // RNE
    return (unsigned short)(x >> 16);
}
__device__ __forceinline__ float bf2f(unsigned short u) {
    return __uint_as_float(((unsigned int)u) << 16);
}

__device__ __forceinline__ int edge_val(const int* __restrict__ ei, int is64, long long idx) {
    return is64 ? ei[2 * idx] : ei[idx];
}

// Detect whether edge_index is int64 (little-endian: odd 4-byte words are 0).
__global__ void detect_kernel(const unsigned int* __restrict__ ei, int* __restrict__ flag) {
    int lane = threadIdx.x;
    unsigned int v = ei[2 * lane + 1];
    unsigned long long b = __ballot(v != 0u);
    if (lane == 0) *flag = (b == 0ull) ? 1 : 0;
}

__global__ __launch_bounds__(256) void zero2_kernel(int* __restrict__ a, int* __restrict__ b, int n) {
    int i = blockIdx.x * blockDim.x + threadIdx.x;
    if (i < n) { a[i] = 0; b[i] = 0; }
}

__global__ __launch_bounds__(256) void sentinel_kernel(float* __restrict__ out, int n, float v) {
    int i = blockIdx.x * blockDim.x + threadIdx.x;
    if (i < n) out[i] = v;
}

__global__ __launch_bounds__(256) void count_kernel(const int* __restrict__ ei,
                                                    const int* __restrict__ flag,
                                                    int E, int N, int* __restrict__ counts) {
    int e = blockIdx.x * blockDim.x + threadIdx.x;
    if (e >= E + N) return;
    int is64 = *flag;
    int d = (e < E) ? edge_val(ei, is64, (long long)E + e) : (e - E);
    atomicAdd(&counts[d], 1);
}

// ---- blocked exclusive scan: per-block scan + block sums (coalesced) ----
__global__ __launch_bounds__(256) void scan_block_kernel(const int* __restrict__ counts,
                                                         int* __restrict__ ptrArr,
                                                         int* __restrict__ bsums, int N) {
    __shared__ int sh[256];
    int t = threadIdx.x, i = blockIdx.x * 256 + t;
    int v = (i < N) ? counts[i] : 0;
    sh[t] = v;
    __syncthreads();
    for (int off = 1; off < 256; off <<= 1) {
        int u = (t >= off) ? sh[t - off] : 0;
        __syncthreads();
        sh[t] += u;
        __syncthreads();
    }
    if (i < N) ptrArr[i] = sh[t] - v;  // exclusive within block
    if (t == 255) bsums[blockIdx.x] = sh[255];
}

__global__ __launch_bounds__(1024) void scan_tops_kernel(const int* __restrict__ bsums,
                                                         int* __restrict__ boff, int nb,
                                                         int* __restrict__ totalOut) {
    __shared__ int sh[1024];
    int t = threadIdx.x;
    int v = (t < nb) ? bsums[t] : 0;
    sh[t] = v;
    __syncthreads();
    for (int off = 1; off < 1024; off <<= 1) {
        int u = (t >= off) ? sh[t - off] : 0;
        __syncthreads();
        sh[t] += u;
        __syncthreads();
    }
    if (t < nb) boff[t] = sh[t] - v;
    if (t == 1023) *totalOut = sh[1023];
}

__global__ __launch_bounds__(256) void scan_add_kernel(int* __restrict__ ptrArr,
                                                       const int* __restrict__ boff, int N) {
    int i = blockIdx.x * blockDim.x + threadIdx.x;
    if (i < N) ptrArr[i] += boff[i >> 8];
}

__global__ __launch_bounds__(256) void fill_kernel(const int* __restrict__ ei,
                                                   const int* __restrict__ flag,
                                                   int E, int N,
                                                   const int* __restrict__ ptrArr,
                                                   int* __restrict__ cursor,
                                                   int* __restrict__ csr_src) {
    int e = blockIdx.x * blockDim.x + threadIdx.x;
    if (e >= E + N) return;
    int is64 = *flag;
    int s, d;
    if (e < E) {
        s = edge_val(ei, is64, e);
        d = edge_val(ei, is64, (long long)E + e);
    } else {
        s = d = e - E;
    }
    int slot = atomicAdd(&cursor[d], 1);
    csr_src[ptrArr[d] + slot] = s;
}

// ---- W [K][N] fp32 -> Wt [N][K] bf16 ----
__global__ __launch_bounds__(256) void transpose_w_kernel(const float* __restrict__ W,
                                                          unsigned short* __restrict__ Wt,
                                                          int K, int Nn) {
    int i = blockIdx.x * blockDim.x + threadIdx.x;
    if (i >= K * Nn) return;
    int n = i / K, k = i - n * K;
    Wt[i] = f2bf(W[(size_t)k * Nn + n]);
}

// ---------------------------------------------------------------------------
// MFMA bf16 GEMM: C[M,N] = A[M,K] @ Bt[N,K]^T. BM=BN=128, BK=64, 256 thr
// (4 waves, each 64x64 via 4x4 frags of 16x16x32). XOR-swizzled LDS (T2).
// A: fp32 (converted in staging) or bf16(ushort). C: bf16(ushort).
// ---------------------------------------------------------------------------
template <typename TA>
__global__ __launch_bounds__(256) void mfma_gemm_kernel(const TA* __restrict__ A,
                                                        const unsigned short* __restrict__ Bt,
                                                        unsigned short* __restrict__ C,
                                                        int M, int K, int N) {
    __shared__ unsigned short As[128 * 64];
    __shared__ unsigned short Bs[128 * 64];
    const int bm = blockIdx.y, bn = blockIdx.x;
    const int tid = threadIdx.x;
    const int lane = tid & 63, wid = tid >> 6;
    const int wr = wid >> 1, wc = wid & 1;
    const int l15 = lane & 15, l4 = lane >> 4;
    f32x4 acc[4][4];
#pragma unroll
    for (int m = 0; m < 4; ++m)
#pragma unroll
        for (int n = 0; n < 4; ++n) acc[m][n] = (f32x4){0.f, 0.f, 0.f, 0.f};

    for (int k0 = 0; k0 < K; k0 += 64) {
        // ---- stage A tile (128 rows x 64 k) bf16, 16B-unit XOR swizzle ----
        if constexpr (sizeof(TA) == 4) {
#pragma unroll
            for (int it = 0; it < 8; ++it) {
                int idx = it * 256 + tid;
                int row = idx >> 4, ch = idx & 15;  // ch = 4-float unit
                int grow = bm * 128 + row;
                fx4 v = {0.f, 0.f, 0.f, 0.f};
                if (grow < M) v = *(const fx4*)((const float*)A + (size_t)grow * K + k0 + ch * 4);
                alignas(8) unsigned short h[4] = {f2bf(v[0]), f2bf(v[1]), f2bf(v[2]), f2bf(v[3])};
                int dst = row * 128 + ((ch * 8) ^ ((row & 7) << 4));
                *(uint2*)((char*)As + dst) = *(uint2*)h;
            }
        } else {
#pragma unroll
            for (int it = 0; it < 4; ++it) {
                int idx = it * 256 + tid;
                int row = idx >> 3, ch = idx & 7;   // ch = 8-bf16 unit
                int grow = bm * 128 + row;
                int4 v = {0, 0, 0, 0};
                if (grow < M) v = *(const int4*)((const unsigned short*)A + (size_t)grow * K + k0 + ch * 8);
                int dst = row * 128 + ((ch * 16) ^ ((row & 7) << 4));
                *(int4*)((char*)As + dst) = v;
            }
        }
        // ---- stage B tile (128 cols x 64 k from Bt rows) ----
#pragma unroll
        for (int it = 0; it < 4; ++it) {
            int idx = it * 256 + tid;
            int row = idx >> 3, ch = idx & 7;
            int4 v = *(const int4*)(Bt + (size_t)(bn * 128 + row) * K + k0 + ch * 8);
            int dst = row * 128 + ((ch * 16) ^ ((row & 7) << 4));
            *(int4*)((char*)Bs + dst) = v;
        }
        __syncthreads();
#pragma unroll
        for (int step = 0; step < 2; ++step) {
            bf16x8 af[4], bfr[4];
            int kb = step * 64 + l4 * 16;
#pragma unroll
            for (int m = 0; m < 4; ++m) {
                int r = wr * 64 + m * 16 + l15;
                af[m] = *(const bf16x8*)((const char*)As + r * 128 + (kb ^ ((r & 7) << 4)));
            }
#pragma unroll
            for (int n = 0; n < 4; ++n) {
                int r = wc * 64 + n * 16 + l15;
                bfr[n] = *(const bf16x8*)((const char*)Bs + r * 128 + (kb ^ ((r & 7) << 4)));
            }
#pragma unroll
            for (int m = 0; m < 4; ++m)
#pragma unroll
                for (int n = 0; n < 4; ++n)
                    acc[m][n] = __builtin_amdgcn_mfma_f32_16x16x32_bf16(af[m], bfr[n], acc[m][n], 0, 0, 0);
        }
        __syncthreads();
    }
    // ---- epilogue: C/D layout col=lane&15, row=(lane>>4)*4+reg ----
#pragma unroll
    for (int m = 0; m < 4; ++m)
#pragma unroll
        for (int j = 0; j < 4; ++j) {
            int row = bm * 128 + wr * 64 + m * 16 + l4 * 4 + j;
            if (row < M) {
#pragma unroll
                for (int n = 0; n < 4; ++n) {
                    int col = bn * 128 + wc * 64 + n * 16 + l15;
                    C[(size_t)row * N + col] = f2bf(acc[m][n][j]);
                }
            }
        }
}

// ---------------------------------------------------------------------------
// alpha dots: all H=4 heads in one vectorized pass. 16 lanes per head.
// ---------------------------------------------------------------------------
template <int H, int C>
__global__ __launch_bounds__(256) void alpha_kernel(const unsigned short* __restrict__ h,
                                                    const float* __restrict__ a_s,
                                                    const float* __restrict__ a_d,
                                                    float* __restrict__ out_s,
                                                    float* __restrict__ out_d, int N) {
    constexpr int F = H * C;
    constexpr int VPL = F / 64;
    int lane = threadIdx.x & 63;
    int wid = threadIdx.x >> 6;
    int n = blockIdx.x * (blockDim.x >> 6) + wid;
    if (n >= N) return;
    const unsigned short* hp = h + (size_t)n * F + lane * VPL;
    alignas(16) unsigned short v[VPL];
    if constexpr (VPL == 8) *(int4*)v = *(const int4*)hp;
    else *(uint2*)v = *(const uint2*)hp;
    int j0 = lane * VPL;
    int head = j0 / C, cb = j0 % C;
    float ps = 0.f, pd = 0.f;
#pragma unroll
    for (int t = 0; t < VPL; ++t) {
        float x = bf2f(v[t]);
        ps += x * a_s[head * C + cb + t];
        pd += x * a_d[head * C + cb + t];
    }
#pragma unroll
    for (int off = 1; off < 16; off <<= 1) {
        ps += __shfl_xor(ps, off);
        pd += __shfl_xor(pd, off);
    }
    if ((lane & 15) == 0) {
        out_s[(size_t)n * H + head] = ps;
        out_d[(size_t)n * H + head] = pd;
    }
}

// ---------------------------------------------------------------------------
// Segment softmax per dst node. Fast path deg<=64: one lane per edge, single
// gather of float4 logits. Fallback: generic 3-pass loop.
// ---------------------------------------------------------------------------
template <int H>
__global__ __launch_bounds__(256) void softmax_kernel(const int* __restrict__ ptrArr,
                                                      const int* __restrict__ csr_src,
                                                      const float* __restrict__ as,
                                                      const float* __restrict__ ad,
                                                      float* __restrict__ alpha_ws, int N) {
    int lane = threadIdx.x & 63;
    int wid = threadIdx.x >> 6;
    int n = blockIdx.x * (blockDim.x >> 6) + wid;
    if (n >= N) return;
    int beg = ptrArr[n], end = ptrArr[n + 1];
    int deg = end - beg;
    if (deg <= 64) {
        bool act = lane < deg;
        int i = beg + (act ? lane : 0);
        int s = csr_src[i];
        float e[H];
        if constexpr (H == 4) {
            fx4 av = *(const fx4*)(as + (size_t)s * 4);
            fx4 dv = *(const fx4*)(ad + (size_t)n * 4);
#pragma unroll
            for (int hh = 0; hh < 4; ++hh) {
                float x = av[hh] + dv[hh];
                x = (x >= 0.f) ? x : LEAKY_SLOPE * x;
                e[hh] = act ? x : -INFINITY;
            }
        } else {
            float x = as[s] + ad[n];
            x = (x >= 0.f) ? x : LEAKY_SLOPE * x;
            e[0] = act ? x : -INFINITY;
        }
#pragma unroll
        for (int hh = 0; hh < H; ++hh) {
            float mm = e[hh];
#pragma unroll
            for (int off = 32; off; off >>= 1) mm = fmaxf(mm, __shfl_xor(mm, off));
            float ex = expf(e[hh] - mm);  // inactive: exp(-inf)=0
            float ss = ex;
#pragma unroll
            for (int off = 32; off; off >>= 1) ss += __shfl_xor(ss, off);
            e[hh] = ex / (ss + 1e-16f);
        }
        if (act) {
            if constexpr (H == 4) {
                fx4 r = {e[0], e[1], e[2], e[3]};
                *(fx4*)(alpha_ws + (size_t)i * 4) = r;
            } else {
                alpha_ws[i] = e[0];
            }
        }
    } else {
        // generic fallback (rare)
#pragma unroll
        for (int hh = 0; hh < H; ++hh) {
            float advv = ad[(size_t)n * H + hh];
            float m = -INFINITY;
            for (int i = beg + lane; i < end; i += 64) {
                int s = csr_src[i];
                float v = as[(size_t)s * H + hh] + advv;
                v = (v >= 0.f) ? v : LEAKY_SLOPE * v;
                m = fmaxf(m, v);
            }
#pragma unroll
            for (int off = 32; off; off >>= 1) m = fmaxf(m, __shfl_xor(m, off));
            float ssum = 0.f;
            for (int i = beg + lane; i < end; i += 64) {
                int s = csr_src[i];
                float v = as[(size_t)s * H + hh] + advv;
                v = (v >= 0.f) ? v : LEAKY_SLOPE * v;
                ssum += expf(v - m);
            }
#pragma unroll
            for (int off = 32; off; off >>= 1) ssum += __shfl_xor(ssum, off);
            float inv = 1.f / (ssum + 1e-16f);
            for (int i = beg + lane; i < end; i += 64) {
                int s = csr_src[i];
                float v = as[(size_t)s * H + hh] + advv;
                v = (v >= 0.f) ? v : LEAKY_SLOPE * v;
                alpha_ws[(size_t)i * H + hh] = expf(v - m) * inv;
            }
        }
    }
}

// ---------------------------------------------------------------------------
// Aggregate: out[n,:] = sum alpha_e * h[src_e,:] + b (+ELU). 16B/8B loads/lane.
// ---------------------------------------------------------------------------
template <int H, int C, bool DO_ELU>
__global__ __launch_bounds__(256) void aggregate_kernel(const int* __restrict__ ptrArr,
                                                        const int* __restrict__ csr_src,
                                                        const float* __restrict__ alpha_ws,
                                                        const unsigned short* __restrict__ hmat,
                                                        const float* __restrict__ bias,
                                                        unsigned short* __restrict__ out, int N) {
    constexpr int F = H * C;
    constexpr int VPL = F / 64;
    int lane = threadIdx.x & 63;
    int wid = threadIdx.x >> 6;
    int n = blockIdx.x * (blockDim.x >> 6) + wid;
    if (n >= N) return;
    int beg = ptrArr[n], end = ptrArr[n + 1];
    int head = (lane * VPL) / C;
    float acc[VPL];
#pragma unroll
    for (int t = 0; t < VPL; ++t) acc[t] = 0.f;
    for (int i = beg; i < end; ++i) {
        int s = csr_src[i];
        float al = alpha_ws[(size_t)i * H + head];
        const unsigned short* hp = hmat + (size_t)s * F + lane * VPL;
        alignas(16) unsigned short v[VPL];
        if constexpr (VPL == 8) *(int4*)v = *(const int4*)hp;
        else *(uint2*)v = *(const uint2*)hp;
#pragma unroll
        for (int t = 0; t < VPL; ++t) acc[t] += al * bf2f(v[t]);
    }
    alignas(16) unsigned short o[VPL];
#pragma unroll
    for (int t = 0; t < VPL; ++t) {
        float x = acc[t] + bias[lane * VPL + t];
        if (DO_ELU) x = (x > 0.f) ? x : expm1f(x);
        o[t] = f2bf(x);
    }
    unsigned short* op = out + (size_t)n * F + lane * VPL;
    if constexpr (VPL == 8) *(int4*)op = *(int4*)o;
    else *(uint2*)op = *(uint2*)o;
}

// ---------------------------------------------------------------------------
// Layer 3: h3 = x3 @ W3 (K=256, 2 cols) fused with alpha dots. One wave/node.
// ---------------------------------------------------------------------------
__global__ __launch_bounds__(256) void layer3_gemm_kernel(const unsigned short* __restrict__ x,
                                                          const float* __restrict__ W,
                                                          const float* __restrict__ a_s,
                                                          const float* __restrict__ a_d,
                                                          float* __restrict__ h3,
                                                          float* __restrict__ out_s,
                                                          float* __restrict__ out_d, int N) {
    int lane = threadIdx.x & 63;
    int wid = threadIdx.x >> 6;
    int n = blockIdx.x * (blockDim.x >> 6) + wid;
    if (n >= N) return;
    const unsigned short* xr = x + (size_t)n * 256 + lane * 4;
    alignas(8) unsigned short v[4];
    *(uint2*)v = *(const uint2*)xr;
    int k0 = lane * 4;
    fx4 w0 = *(const fx4*)(W + k0 * 2);
    fx4 w1 = *(const fx4*)(W + k0 * 2 + 4);
    float a0 = bf2f(v[0]) * w0[0] + bf2f(v[1]) * w0[2] + bf2f(v[2]) * w1[0] + bf2f(v[3]) * w1[2];
    float a1 = bf2f(v[0]) * w0[1] + bf2f(v[1]) * w0[3] + bf2f(v[2]) * w1[1] + bf2f(v[3]) * w1[3];
#pragma unroll
    for (int off = 32; off; off >>= 1) {
        a0 += __shfl_xor(a0, off);
        a1 += __shfl_xor(a1, off);
    }
    if (lane == 0) {
        h3[(size_t)n * 2 + 0] = a0;
        h3[(size_t)n * 2 + 1] = a1;
        out_s[n] = a0 * a_s[0] + a1 * a_s[1];
        out_d[n] = a0 * a_d[0] + a1 * a_d[1];
    }
}

__global__ __launch_bounds__(256) void aggregate3_kernel(const int* __restrict__ ptrArr,
                                                         const int* __restrict__ csr_src,
                                                         const float* __restrict__ alpha_ws,
                                                         const float* __restrict__ h3,
                                                         const float* __restrict__ b3,
                                                         float* __restrict__ out, int N) {
    int n = blockIdx.x * blockDim.x + threadIdx.x;
    if (n >= N) return;
    float a0 = 0.f, a1 = 0.f;
    int beg = ptrArr[n], end = ptrArr[n + 1];
    for (int i = beg; i < end; ++i) {
        int s = csr_src[i];
        float al = alpha_ws[i];
        a0 += al * h3[(size_t)s * 2 + 0];
        a1 += al * h3[(size_t)s * 2 + 1];
    }
    out[(size_t)n * 2 + 0] = a0 + b3[0];
    out[(size_t)n * 2 + 1] = a1 + b3[1];
}

// ---------------------------------------------------------------------------

extern "C" void kernel_launch(void* const* d_in, const int* in_sizes, int n_in,
                              void* d_out, int out_size, void* d_ws, size_t ws_size,
                              hipStream_t stream) {
    const float* x      = (const float*)d_in[0];
    const int*   ei     = (const int*)d_in[1];
    const float* W1     = (const float*)d_in[2];
    const float* a_src1 = (const float*)d_in[3];
    const float* a_dst1 = (const float*)d_in[4];
    const float* b1     = (const float*)d_in[5];
    const float* W2     = (const float*)d_in[6];
    const float* a_src2 = (const float*)d_in[7];
    const float* a_dst2 = (const float*)d_in[8];
    const float* b2     = (const float*)d_in[9];
    const float* W3     = (const float*)d_in[10];
    const float* a_src3 = (const float*)d_in[11];
    const float* a_dst3 = (const float*)d_in[12];
    const float* b3     = (const float*)d_in[13];

    const int N = in_sizes[0] / 128;
    const int E = in_sizes[1] / 2;
    const int ET = E + N;
    const int nb = (N + 255) / 256;  // scan blocks (<=1024 required; 391 here)

    // ---- workspace carve (256B aligned), with explicit size guard ----
    size_t need = 0;
    auto carve = [&](size_t bytes) -> size_t {
        size_t off = need;
        need += (bytes + 255) & ~(size_t)255;
        return off;
    };
    size_t o_counts   = carve((size_t)N * 4);
    size_t o_cursor   = carve((size_t)N * 4);
    size_t o_ptr      = carve((size_t)(N + 1) * 4);
    size_t o_csr      = carve((size_t)ET * 4);
    size_t o_flag     = carve(4);
    size_t o_bsums    = carve((size_t)2048 * 4);
    size_t o_boff     = carve((size_t)2048 * 4);
    size_t o_alpha_s  = carve((size_t)N * 4 * 4);
    size_t o_alpha_d  = carve((size_t)N * 4 * 4);
    size_t o_alpha_ws = carve((size_t)ET * 4 * 4);
    size_t o_h3       = carve((size_t)N * 2 * 4);
    size_t o_wt1      = carve((size_t)512 * 128 * 2);
    size_t o_wt2      = carve((size_t)256 * 512 * 2);
    size_t o_bufA     = carve((size_t)N * 512 * 2);  // bf16
    size_t o_bufB     = carve((size_t)N * 512 * 2);  // bf16

    if (need > ws_size) {
        sentinel_kernel<<<(out_size + 255) / 256, 256, 0, stream>>>(
            (float*)d_out, out_size, (float)(ws_size >> 20));
        return;
    }

    char* w = (char*)d_ws;
    int*   counts   = (int*)(w + o_counts);
    int*   cursor   = (int*)(w + o_cursor);
    int*   ptrArr   = (int*)(w + o_ptr);
    int*   csr_src  = (int*)(w + o_csr);
    int*   flag     = (int*)(w + o_flag);
    int*   bsums    = (int*)(w + o_bsums);
    int*   boff     = (int*)(w + o_boff);
    float* alpha_s  = (float*)(w + o_alpha_s);
    float* alpha_d  = (float*)(w + o_alpha_d);
    float* alpha_ws = (float*)(w + o_alpha_ws);
    float* h3       = (float*)(w + o_h3);
    unsigned short* Wt1  = (unsigned short*)(w + o_wt1);
    unsigned short* Wt2  = (unsigned short*)(w + o_wt2);
    unsigned short* bufA = (unsigned short*)(w + o_bufA);
    unsigned short* bufB = (unsigned short*)(w + o_bufB);

    const int edge_blocks = (ET + 255) / 256;
    const int node_wave_blocks = (N + 3) / 4;
    const int node_thr_blocks = (N + 255) / 256;

    // ---- CSR build ----
    zero2_kernel<<<node_thr_blocks, 256, 0, stream>>>(counts, cursor, N);
    detect_kernel<<<1, 64, 0, stream>>>((const unsigned int*)ei, flag);
    count_kernel<<<edge_blocks, 256, 0, stream>>>(ei, flag, E, N, counts);
    scan_block_kernel<<<nb, 256, 0, stream>>>(counts, ptrArr, bsums, N);
    scan_tops_kernel<<<1, 1024, 0, stream>>>(bsums, boff, nb, ptrArr + N);
    scan_add_kernel<<<node_thr_blocks, 256, 0, stream>>>(ptrArr, boff, N);
    fill_kernel<<<edge_blocks, 256, 0, stream>>>(ei, flag, E, N, ptrArr, cursor, csr_src);

    // ---- weight transposes (bf16) ----
    transpose_w_kernel<<<(512 * 128 + 255) / 256, 256, 0, stream>>>(W1, Wt1, 128, 512);
    transpose_w_kernel<<<(256 * 512 + 255) / 256, 256, 0, stream>>>(W2, Wt2, 512, 256);

    // ---- Layer 1: 128 -> 4x128, concat, ELU ----
    {
        dim3 g(512 / 128, (N + 127) / 128);
        mfma_gemm_kernel<float><<<g, 256, 0, stream>>>(x, Wt1, bufA, N, 128, 512);
        alpha_kernel<4, 128><<<node_wave_blocks, 256, 0, stream>>>(bufA, a_src1, a_dst1, alpha_s, alpha_d, N);
        softmax_kernel<4><<<node_wave_blocks, 256, 0, stream>>>(ptrArr, csr_src, alpha_s, alpha_d, alpha_ws, N);
        aggregate_kernel<4, 128, true><<<node_wave_blocks, 256, 0, stream>>>(ptrArr, csr_src, alpha_ws, bufA, b1, bufB, N);
    }
    // ---- Layer 2: 512 -> 4x64, concat, ELU ----
    {
        dim3 g(256 / 128, (N + 127) / 128);
        mfma_gemm_kernel<unsigned short><<<g, 256, 0, stream>>>(bufB, Wt2, bufA, N, 512, 256);
        alpha_kernel<4, 64><<<node_wave_blocks, 256, 0, stream>>>(bufA, a_src2, a_dst2, alpha_s, alpha_d, N);
        softmax_kernel<4><<<node_wave_blocks, 256, 0, stream>>>(ptrArr, csr_src, alpha_s, alpha_d, alpha_ws, N);
        aggregate_kernel<4, 64, true><<<node_wave_blocks, 256, 0, stream>>>(ptrArr, csr_src, alpha_ws, bufA, b2, bufB, N);
    }
    // ---- Layer 3: 256 -> 2, heads=1, mean(=identity), no ELU ----
    {
        layer3_gemm_kernel<<<node_wave_blocks, 256, 0, stream>>>(bufB, W3, a_src3, a_dst3, h3, alpha_s, alpha_d, N);
        softmax_kernel<1><<<node_wave_blocks, 256, 0, stream>>>(ptrArr, csr_src, alpha_s, alpha_d, alpha_ws, N);
        aggregate3_kernel<<<node_thr_blocks, 256, 0, stream>>>(ptrArr, csr_src, alpha_ws, h3, b3, (float*)d_out, N);
    }
}

// Round 4
// 568.385 us; speedup vs baseline: 2.3172x; 1.0217x over previous
//
#include <hip/hip_runtime.h>
#include <hip/hip_bf16.h>
#include <math.h>

// ---------------------------------------------------------------------------
// GAT (3x GATConv, PyG-style) on MI355X. Round 3: alpha dots fused into GEMM
// epilogue; aggregate gather 4-deep edge-unrolled (MLP fix for latency-bound
// random row gather). MFMA bf16 GEMMs 128x128x64, XOR-swizzled LDS.
// ---------------------------------------------------------------------------

#define LEAKY_SLOPE 0.2f

typedef __attribute__((ext_vector_type(8))) short bf16x8;
typedef __attribute__((ext_vector_type(4))) float f32x4;
typedef __attribute__((ext_vector_type(4))) float fx4;

__device__ __forceinline__ unsigned short f2bf(float f) {
    unsigned int x = __float_as_uint(f);
    x += 0x7fffu + ((x >> 16) & 1u);   // RNE
    return (unsigned short)(x >> 16);
}
__device__ __forceinline__ float bf2f(unsigned short u) {
    return __uint_as_float(((unsigned int)u) << 16);
}

__device__ __forceinline__ int edge_val(const int* __restrict__ ei, int is64, long long idx) {
    return is64 ? ei[2 * idx] : ei[idx];
}

// Detect whether edge_index is int64 (little-endian: odd 4-byte words are 0).
__global__ void detect_kernel(const unsigned int* __restrict__ ei, int* __restrict__ flag) {
    int lane = threadIdx.x;
    unsigned int v = ei[2 * lane + 1];
    unsigned long long b = __ballot(v != 0u);
    if (lane == 0) *flag = (b == 0ull) ? 1 : 0;
}

__global__ __launch_bounds__(256) void zero2_kernel(int* __restrict__ a, int* __restrict__ b, int n) {
    int i = blockIdx.x * blockDim.x + threadIdx.x;
    if (i < n) { a[i] = 0; b[i] = 0; }
}

__global__ __launch_bounds__(256) void sentinel_kernel(float* __restrict__ out, int n, float v) {
    int i = blockIdx.x * blockDim.x + threadIdx.x;
    if (i < n) out[i] = v;
}

__global__ __launch_bounds__(256) void count_kernel(const int* __restrict__ ei,
                                                    const int* __restrict__ flag,
                                                    int E, int N, int* __restrict__ counts) {
    int e = blockIdx.x * blockDim.x + threadIdx.x;
    if (e >= E + N) return;
    int is64 = *flag;
    int d = (e < E) ? edge_val(ei, is64, (long long)E + e) : (e - E);
    atomicAdd(&counts[d], 1);
}

// ---- blocked exclusive scan ----
__global__ __launch_bounds__(256) void scan_block_kernel(const int* __restrict__ counts,
                                                         int* __restrict__ ptrArr,
                                                         int* __restrict__ bsums, int N) {
    __shared__ int sh[256];
    int t = threadIdx.x, i = blockIdx.x * 256 + t;
    int v = (i < N) ? counts[i] : 0;
    sh[t] = v;
    __syncthreads();
    for (int off = 1; off < 256; off <<= 1) {
        int u = (t >= off) ? sh[t - off] : 0;
        __syncthreads();
        sh[t] += u;
        __syncthreads();
    }
    if (i < N) ptrArr[i] = sh[t] - v;
    if (t == 255) bsums[blockIdx.x] = sh[255];
}

__global__ __launch_bounds__(1024) void scan_tops_kernel(const int* __restrict__ bsums,
                                                         int* __restrict__ boff, int nb,
                                                         int* __restrict__ totalOut) {
    __shared__ int sh[1024];
    int t = threadIdx.x;
    int v = (t < nb) ? bsums[t] : 0;
    sh[t] = v;
    __syncthreads();
    for (int off = 1; off < 1024; off <<= 1) {
        int u = (t >= off) ? sh[t - off] : 0;
        __syncthreads();
        sh[t] += u;
        __syncthreads();
    }
    if (t < nb) boff[t] = sh[t] - v;
    if (t == 1023) *totalOut = sh[1023];
}

__global__ __launch_bounds__(256) void scan_add_kernel(int* __restrict__ ptrArr,
                                                       const int* __restrict__ boff, int N) {
    int i = blockIdx.x * blockDim.x + threadIdx.x;
    if (i < N) ptrArr[i] += boff[i >> 8];
}

__global__ __launch_bounds__(256) void fill_kernel(const int* __restrict__ ei,
                                                   const int* __restrict__ flag,
                                                   int E, int N,
                                                   const int* __restrict__ ptrArr,
                                                   int* __restrict__ cursor,
                                                   int* __restrict__ csr_src) {
    int e = blockIdx.x * blockDim.x + threadIdx.x;
    if (e >= E + N) return;
    int is64 = *flag;
    int s, d;
    if (e < E) {
        s = edge_val(ei, is64, e);
        d = edge_val(ei, is64, (long long)E + e);
    } else {
        s = d = e - E;
    }
    int slot = atomicAdd(&cursor[d], 1);
    csr_src[ptrArr[d] + slot] = s;
}

// ---- W [K][N] fp32 -> Wt [N][K] bf16 ----
__global__ __launch_bounds__(256) void transpose_w_kernel(const float* __restrict__ W,
                                                          unsigned short* __restrict__ Wt,
                                                          int K, int Nn) {
    int i = blockIdx.x * blockDim.x + threadIdx.x;
    if (i >= K * Nn) return;
    int n = i / K, k = i - n * K;
    Wt[i] = f2bf(W[(size_t)k * Nn + n]);
}

// ---------------------------------------------------------------------------
// MFMA bf16 GEMM: C[M,N] = A[M,K] @ Bt[N,K]^T. BM=BN=128, BK=64, 256 thr
// (4 waves, each 64x64 via 4x4 frags of 16x16x32). XOR-swizzled LDS (T2).
// C_HEAD>0: fused alpha epilogue. Each wave's 64 cols = one head (C_HEAD=64)
// or half a head (C_HEAD=128, LDS-combined across the 2 col-waves).
// a_src/a_dst flat over [H][C] == flat col index (head*C + c == col).
// ---------------------------------------------------------------------------
template <typename TA, int C_HEAD>
__global__ __launch_bounds__(256) void mfma_gemm_kernel(const TA* __restrict__ A,
                                                        const unsigned short* __restrict__ Bt,
                                                        unsigned short* __restrict__ C,
                                                        const float* __restrict__ a_src,
                                                        const float* __restrict__ a_dst,
                                                        float* __restrict__ alpha_s,
                                                        float* __restrict__ alpha_d,
                                                        int M, int K, int N) {
    __shared__ unsigned short As[128 * 64];
    __shared__ unsigned short Bs[128 * 64];
    const int bm = blockIdx.y, bn = blockIdx.x;
    const int tid = threadIdx.x;
    const int lane = tid & 63, wid = tid >> 6;
    const int wr = wid >> 1, wc = wid & 1;
    const int l15 = lane & 15, l4 = lane >> 4;
    f32x4 acc[4][4];
#pragma unroll
    for (int m = 0; m < 4; ++m)
#pragma unroll
        for (int n = 0; n < 4; ++n) acc[m][n] = (f32x4){0.f, 0.f, 0.f, 0.f};

    for (int k0 = 0; k0 < K; k0 += 64) {
        if constexpr (sizeof(TA) == 4) {
#pragma unroll
            for (int it = 0; it < 8; ++it) {
                int idx = it * 256 + tid;
                int row = idx >> 4, ch = idx & 15;
                int grow = bm * 128 + row;
                fx4 v = {0.f, 0.f, 0.f, 0.f};
                if (grow < M) v = *(const fx4*)((const float*)A + (size_t)grow * K + k0 + ch * 4);
                alignas(8) unsigned short h[4] = {f2bf(v[0]), f2bf(v[1]), f2bf(v[2]), f2bf(v[3])};
                int dst = row * 128 + ((ch * 8) ^ ((row & 7) << 4));
                *(uint2*)((char*)As + dst) = *(uint2*)h;
            }
        } else {
#pragma unroll
            for (int it = 0; it < 4; ++it) {
                int idx = it * 256 + tid;
                int row = idx >> 3, ch = idx & 7;
                int grow = bm * 128 + row;
                int4 v = {0, 0, 0, 0};
                if (grow < M) v = *(const int4*)((const unsigned short*)A + (size_t)grow * K + k0 + ch * 8);
                int dst = row * 128 + ((ch * 16) ^ ((row & 7) << 4));
                *(int4*)((char*)As + dst) = v;
            }
        }
#pragma unroll
        for (int it = 0; it < 4; ++it) {
            int idx = it * 256 + tid;
            int row = idx >> 3, ch = idx & 7;
            int4 v = *(const int4*)(Bt + (size_t)(bn * 128 + row) * K + k0 + ch * 8);
            int dst = row * 128 + ((ch * 16) ^ ((row & 7) << 4));
            *(int4*)((char*)Bs + dst) = v;
        }
        __syncthreads();
#pragma unroll
        for (int step = 0; step < 2; ++step) {
            bf16x8 af[4], bfr[4];
            int kb = step * 64 + l4 * 16;
#pragma unroll
            for (int m = 0; m < 4; ++m) {
                int r = wr * 64 + m * 16 + l15;
                af[m] = *(const bf16x8*)((const char*)As + r * 128 + (kb ^ ((r & 7) << 4)));
            }
#pragma unroll
            for (int n = 0; n < 4; ++n) {
                int r = wc * 64 + n * 16 + l15;
                bfr[n] = *(const bf16x8*)((const char*)Bs + r * 128 + (kb ^ ((r & 7) << 4)));
            }
#pragma unroll
            for (int m = 0; m < 4; ++m)
#pragma unroll
                for (int n = 0; n < 4; ++n)
                    acc[m][n] = __builtin_amdgcn_mfma_f32_16x16x32_bf16(af[m], bfr[n], acc[m][n], 0, 0, 0);
        }
        __syncthreads();
    }
    // ---- C store: C/D layout col=lane&15, row=(lane>>4)*4+reg ----
#pragma unroll
    for (int m = 0; m < 4; ++m)
#pragma unroll
        for (int j = 0; j < 4; ++j) {
            int row = bm * 128 + wr * 64 + m * 16 + l4 * 4 + j;
            if (row < M) {
#pragma unroll
                for (int n = 0; n < 4; ++n) {
                    int col = bn * 128 + wc * 64 + n * 16 + l15;
                    C[(size_t)row * N + col] = f2bf(acc[m][n][j]);
                }
            }
        }
    // ---- fused alpha epilogue ----
    if constexpr (C_HEAD > 0) {
        const int H = N / C_HEAD;
        float ps[4][4], pd[4][4];  // [m][j]
#pragma unroll
        for (int m = 0; m < 4; ++m)
#pragma unroll
            for (int j = 0; j < 4; ++j) { ps[m][j] = 0.f; pd[m][j] = 0.f; }
#pragma unroll
        for (int n = 0; n < 4; ++n) {
            int col = bn * 128 + wc * 64 + n * 16 + l15;
            float asv = a_src[col];
            float adv = a_dst[col];
#pragma unroll
            for (int m = 0; m < 4; ++m)
#pragma unroll
                for (int j = 0; j < 4; ++j) {
                    ps[m][j] += acc[m][n][j] * asv;
                    pd[m][j] += acc[m][n][j] * adv;
                }
        }
        // reduce over the 16 l15 lanes (same l4 group)
#pragma unroll
        for (int off = 1; off < 16; off <<= 1)
#pragma unroll
            for (int m = 0; m < 4; ++m)
#pragma unroll
                for (int j = 0; j < 4; ++j) {
                    ps[m][j] += __shfl_xor(ps[m][j], off);
                    pd[m][j] += __shfl_xor(pd[m][j], off);
                }
        if constexpr (C_HEAD == 64) {
            // wave's 64 cols == head (2*bn + wc); direct store
            if (l15 == 0) {
                int head = bn * 2 + wc;
#pragma unroll
                for (int m = 0; m < 4; ++m)
#pragma unroll
                    for (int j = 0; j < 4; ++j) {
                        int row = bm * 128 + wr * 64 + m * 16 + l4 * 4 + j;
                        if (row < M) {
                            alpha_s[(size_t)row * H + head] = ps[m][j];
                            alpha_d[(size_t)row * H + head] = pd[m][j];
                        }
                    }
            }
        } else {
            // C_HEAD==128: combine wc=0 and wc=1 halves via LDS (reuse As)
            float* red = (float*)As;  // [wc*2+sd][128] = 4*128 floats
            if (l15 == 0) {
#pragma unroll
                for (int m = 0; m < 4; ++m)
#pragma unroll
                    for (int j = 0; j < 4; ++j) {
                        int rl = wr * 64 + m * 16 + l4 * 4 + j;
                        red[(wc * 2 + 0) * 128 + rl] = ps[m][j];
                        red[(wc * 2 + 1) * 128 + rl] = pd[m][j];
                    }
            }
            __syncthreads();
            if (wc == 0 && l15 == 0) {
#pragma unroll
                for (int m = 0; m < 4; ++m)
#pragma unroll
                    for (int j = 0; j < 4; ++j) {
                        int rl = wr * 64 + m * 16 + l4 * 4 + j;
                        int row = bm * 128 + rl;
                        if (row < M) {
                            alpha_s[(size_t)row * H + bn] = red[0 * 128 + rl] + red[2 * 128 + rl];
                            alpha_d[(size_t)row * H + bn] = red[1 * 128 + rl] + red[3 * 128 + rl];
                        }
                    }
            }
        }
    }
}

// ---------------------------------------------------------------------------
// Segment softmax per dst node. Fast path deg<=64: one lane per edge.
// ---------------------------------------------------------------------------
template <int H>
__global__ __launch_bounds__(256) void softmax_kernel(const int* __restrict__ ptrArr,
                                                      const int* __restrict__ csr_src,
                                                      const float* __restrict__ as,
                                                      const float* __restrict__ ad,
                                                      float* __restrict__ alpha_ws, int N) {
    int lane = threadIdx.x & 63;
    int wid = threadIdx.x >> 6;
    int n = blockIdx.x * (blockDim.x >> 6) + wid;
    if (n >= N) return;
    int beg = ptrArr[n], end = ptrArr[n + 1];
    int deg = end - beg;
    if (deg <= 64) {
        bool act = lane < deg;
        int i = beg + (act ? lane : 0);
        int s = csr_src[i];
        float e[H];
        if constexpr (H == 4) {
            fx4 av = *(const fx4*)(as + (size_t)s * 4);
            fx4 dv = *(const fx4*)(ad + (size_t)n * 4);
#pragma unroll
            for (int hh = 0; hh < 4; ++hh) {
                float x = av[hh] + dv[hh];
                x = (x >= 0.f) ? x : LEAKY_SLOPE * x;
                e[hh] = act ? x : -INFINITY;
            }
        } else {
            float x = as[s] + ad[n];
            x = (x >= 0.f) ? x : LEAKY_SLOPE * x;
            e[0] = act ? x : -INFINITY;
        }
#pragma unroll
        for (int hh = 0; hh < H; ++hh) {
            float mm = e[hh];
#pragma unroll
            for (int off = 32; off; off >>= 1) mm = fmaxf(mm, __shfl_xor(mm, off));
            float ex = expf(e[hh] - mm);
            float ss = ex;
#pragma unroll
            for (int off = 32; off; off >>= 1) ss += __shfl_xor(ss, off);
            e[hh] = ex / (ss + 1e-16f);
        }
        if (act) {
            if constexpr (H == 4) {
                fx4 r = {e[0], e[1], e[2], e[3]};
                *(fx4*)(alpha_ws + (size_t)i * 4) = r;
            } else {
                alpha_ws[i] = e[0];
            }
        }
    } else {
#pragma unroll
        for (int hh = 0; hh < H; ++hh) {
            float advv = ad[(size_t)n * H + hh];
            float m = -INFINITY;
            for (int i = beg + lane; i < end; i += 64) {
                int s = csr_src[i];
                float v = as[(size_t)s * H + hh] + advv;
                v = (v >= 0.f) ? v : LEAKY_SLOPE * v;
                m = fmaxf(m, v);
            }
#pragma unroll
            for (int off = 32; off; off >>= 1) m = fmaxf(m, __shfl_xor(m, off));
            float ssum = 0.f;
            for (int i = beg + lane; i < end; i += 64) {
                int s = csr_src[i];
                float v = as[(size_t)s * H + hh] + advv;
                v = (v >= 0.f) ? v : LEAKY_SLOPE * v;
                ssum += expf(v - m);
            }
#pragma unroll
            for (int off = 32; off; off >>= 1) ssum += __shfl_xor(ssum, off);
            float inv = 1.f / (ssum + 1e-16f);
            for (int i = beg + lane; i < end; i += 64) {
                int s = csr_src[i];
                float v = as[(size_t)s * H + hh] + advv;
                v = (v >= 0.f) ? v : LEAKY_SLOPE * v;
                alpha_ws[(size_t)i * H + hh] = expf(v - m) * inv;
            }
        }
    }
}

// ---------------------------------------------------------------------------
// Aggregate: out[n,:] = sum alpha_e * h[src_e,:] + b (+ELU).
// 4-deep predicated edge unroll: 4 independent 16B/lane row loads in flight.
// ---------------------------------------------------------------------------
template <int H, int C, bool DO_ELU>
__global__ __launch_bounds__(256) void aggregate_kernel(const int* __restrict__ ptrArr,
                                                        const int* __restrict__ csr_src,
                                                        const float* __restrict__ alpha_ws,
                                                        const unsigned short* __restrict__ hmat,
                                                        const float* __restrict__ bias,
                                                        unsigned short* __restrict__ out, int N) {
    constexpr int F = H * C;
    constexpr int VPL = F / 64;
    int lane = threadIdx.x & 63;
    int wid = threadIdx.x >> 6;
    int n = blockIdx.x * (blockDim.x >> 6) + wid;
    if (n >= N) return;
    int beg = ptrArr[n], end = ptrArr[n + 1];
    int head = (lane * VPL) / C;
    float acc[VPL];
#pragma unroll
    for (int t = 0; t < VPL; ++t) acc[t] = 0.f;
    for (int i = beg; i < end; i += 4) {
        int e1 = (i + 1 < end) ? i + 1 : i;
        int e2 = (i + 2 < end) ? i + 2 : i;
        int e3 = (i + 3 < end) ? i + 3 : i;
        int s0 = csr_src[i], s1 = csr_src[e1], s2 = csr_src[e2], s3 = csr_src[e3];
        float al0 = alpha_ws[(size_t)i * H + head];
        float al1 = (i + 1 < end) ? alpha_ws[(size_t)e1 * H + head] : 0.f;
        float al2 = (i + 2 < end) ? alpha_ws[(size_t)e2 * H + head] : 0.f;
        float al3 = (i + 3 < end) ? alpha_ws[(size_t)e3 * H + head] : 0.f;
        const unsigned short* p0 = hmat + (size_t)s0 * F + lane * VPL;
        const unsigned short* p1 = hmat + (size_t)s1 * F + lane * VPL;
        const unsigned short* p2 = hmat + (size_t)s2 * F + lane * VPL;
        const unsigned short* p3 = hmat + (size_t)s3 * F + lane * VPL;
        alignas(16) unsigned short v0[VPL], v1[VPL], v2[VPL], v3[VPL];
        if constexpr (VPL == 8) {
            *(int4*)v0 = *(const int4*)p0;
            *(int4*)v1 = *(const int4*)p1;
            *(int4*)v2 = *(const int4*)p2;
            *(int4*)v3 = *(const int4*)p3;
        } else {
            *(uint2*)v0 = *(const uint2*)p0;
            *(uint2*)v1 = *(const uint2*)p1;
            *(uint2*)v2 = *(const uint2*)p2;
            *(uint2*)v3 = *(const uint2*)p3;
        }
#pragma unroll
        for (int t = 0; t < VPL; ++t)
            acc[t] += al0 * bf2f(v0[t]) + al1 * bf2f(v1[t]) + al2 * bf2f(v2[t]) + al3 * bf2f(v3[t]);
    }
    alignas(16) unsigned short o[VPL];
#pragma unroll
    for (int t = 0; t < VPL; ++t) {
        float x = acc[t] + bias[lane * VPL + t];
        if (DO_ELU) x = (x > 0.f) ? x : expm1f(x);
        o[t] = f2bf(x);
    }
    unsigned short* op = out + (size_t)n * F + lane * VPL;
    if constexpr (VPL == 8) *(int4*)op = *(int4*)o;
    else *(uint2*)op = *(uint2*)o;
}

// ---------------------------------------------------------------------------
// Layer 3: h3 = x3 @ W3 (K=256, 2 cols) fused with alpha dots. One wave/node.
// ---------------------------------------------------------------------------
__global__ __launch_bounds__(256) void layer3_gemm_kernel(const unsigned short* __restrict__ x,
                                                          const float* __restrict__ W,
                                                          const float* __restrict__ a_s,
                                                          const float* __restrict__ a_d,
                                                          float* __restrict__ h3,
                                                          float* __restrict__ out_s,
                                                          float* __restrict__ out_d, int N) {
    int lane = threadIdx.x & 63;
    int wid = threadIdx.x >> 6;
    int n = blockIdx.x * (blockDim.x >> 6) + wid;
    if (n >= N) return;
    const unsigned short* xr = x + (size_t)n * 256 + lane * 4;
    alignas(8) unsigned short v[4];
    *(uint2*)v = *(const uint2*)xr;
    int k0 = lane * 4;
    fx4 w0 = *(const fx4*)(W + k0 * 2);
    fx4 w1 = *(const fx4*)(W + k0 * 2 + 4);
    float a0 = bf2f(v[0]) * w0[0] + bf2f(v[1]) * w0[2] + bf2f(v[2]) * w1[0] + bf2f(v[3]) * w1[2];
    float a1 = bf2f(v[0]) * w0[1] + bf2f(v[1]) * w0[3] + bf2f(v[2]) * w1[1] + bf2f(v[3]) * w1[3];
#pragma unroll
    for (int off = 32; off; off >>= 1) {
        a0 += __shfl_xor(a0, off);
        a1 += __shfl_xor(a1, off);
    }
    if (lane == 0) {
        h3[(size_t)n * 2 + 0] = a0;
        h3[(size_t)n * 2 + 1] = a1;
        out_s[n] = a0 * a_s[0] + a1 * a_s[1];
        out_d[n] = a0 * a_d[0] + a1 * a_d[1];
    }
}

__global__ __launch_bounds__(256) void aggregate3_kernel(const int* __restrict__ ptrArr,
                                                         const int* __restrict__ csr_src,
                                                         const float* __restrict__ alpha_ws,
                                                         const float* __restrict__ h3,
                                                         const float* __restrict__ b3,
                                                         float* __restrict__ out, int N) {
    int n = blockIdx.x * blockDim.x + threadIdx.x;
    if (n >= N) return;
    float a0 = 0.f, a1 = 0.f;
    int beg = ptrArr[n], end = ptrArr[n + 1];
    for (int i = beg; i < end; ++i) {
        int s = csr_src[i];
        float al = alpha_ws[i];
        a0 += al * h3[(size_t)s * 2 + 0];
        a1 += al * h3[(size_t)s * 2 + 1];
    }
    out[(size_t)n * 2 + 0] = a0 + b3[0];
    out[(size_t)n * 2 + 1] = a1 + b3[1];
}

// ---------------------------------------------------------------------------

extern "C" void kernel_launch(void* const* d_in, const int* in_sizes, int n_in,
                              void* d_out, int out_size, void* d_ws, size_t ws_size,
                              hipStream_t stream) {
    const float* x      = (const float*)d_in[0];
    const int*   ei     = (const int*)d_in[1];
    const float* W1     = (const float*)d_in[2];
    const float* a_src1 = (const float*)d_in[3];
    const float* a_dst1 = (const float*)d_in[4];
    const float* b1     = (const float*)d_in[5];
    const float* W2     = (const float*)d_in[6];
    const float* a_src2 = (const float*)d_in[7];
    const float* a_dst2 = (const float*)d_in[8];
    const float* b2     = (const float*)d_in[9];
    const float* W3     = (const float*)d_in[10];
    const float* a_src3 = (const float*)d_in[11];
    const float* a_dst3 = (const float*)d_in[12];
    const float* b3     = (const float*)d_in[13];

    const int N = in_sizes[0] / 128;
    const int E = in_sizes[1] / 2;
    const int ET = E + N;
    const int nb = (N + 255) / 256;

    size_t need = 0;
    auto carve = [&](size_t bytes) -> size_t {
        size_t off = need;
        need += (bytes + 255) & ~(size_t)255;
        return off;
    };
    size_t o_counts   = carve((size_t)N * 4);
    size_t o_cursor   = carve((size_t)N * 4);
    size_t o_ptr      = carve((size_t)(N + 1) * 4);
    size_t o_csr      = carve((size_t)ET * 4);
    size_t o_flag     = carve(4);
    size_t o_bsums    = carve((size_t)2048 * 4);
    size_t o_boff     = carve((size_t)2048 * 4);
    size_t o_alpha_s  = carve((size_t)N * 4 * 4);
    size_t o_alpha_d  = carve((size_t)N * 4 * 4);
    size_t o_alpha_ws = carve((size_t)ET * 4 * 4);
    size_t o_h3       = carve((size_t)N * 2 * 4);
    size_t o_wt1      = carve((size_t)512 * 128 * 2);
    size_t o_wt2      = carve((size_t)256 * 512 * 2);
    size_t o_bufA     = carve((size_t)N * 512 * 2);
    size_t o_bufB     = carve((size_t)N * 512 * 2);

    if (need > ws_size) {
        sentinel_kernel<<<(out_size + 255) / 256, 256, 0, stream>>>(
            (float*)d_out, out_size, (float)(ws_size >> 20));
        return;
    }

    char* w = (char*)d_ws;
    int*   counts   = (int*)(w + o_counts);
    int*   cursor   = (int*)(w + o_cursor);
    int*   ptrArr   = (int*)(w + o_ptr);
    int*   csr_src  = (int*)(w + o_csr);
    int*   flag     = (int*)(w + o_flag);
    int*   bsums    = (int*)(w + o_bsums);
    int*   boff     = (int*)(w + o_boff);
    float* alpha_s  = (float*)(w + o_alpha_s);
    float* alpha_d  = (float*)(w + o_alpha_d);
    float* alpha_ws = (float*)(w + o_alpha_ws);
    float* h3       = (float*)(w + o_h3);
    unsigned short* Wt1  = (unsigned short*)(w + o_wt1);
    unsigned short* Wt2  = (unsigned short*)(w + o_wt2);
    unsigned short* bufA = (unsigned short*)(w + o_bufA);
    unsigned short* bufB = (unsigned short*)(w + o_bufB);

    const int edge_blocks = (ET + 255) / 256;
    const int node_wave_blocks = (N + 3) / 4;
    const int node_thr_blocks = (N + 255) / 256;

    // ---- CSR build ----
    zero2_kernel<<<node_thr_blocks, 256, 0, stream>>>(counts, cursor, N);
    detect_kernel<<<1, 64, 0, stream>>>((const unsigned int*)ei, flag);
    count_kernel<<<edge_blocks, 256, 0, stream>>>(ei, flag, E, N, counts);
    scan_block_kernel<<<nb, 256, 0, stream>>>(counts, ptrArr, bsums, N);
    scan_tops_kernel<<<1, 1024, 0, stream>>>(bsums, boff, nb, ptrArr + N);
    scan_add_kernel<<<node_thr_blocks, 256, 0, stream>>>(ptrArr, boff, N);
    fill_kernel<<<edge_blocks, 256, 0, stream>>>(ei, flag, E, N, ptrArr, cursor, csr_src);

    // ---- weight transposes (bf16) ----
    transpose_w_kernel<<<(512 * 128 + 255) / 256, 256, 0, stream>>>(W1, Wt1, 128, 512);
    transpose_w_kernel<<<(256 * 512 + 255) / 256, 256, 0, stream>>>(W2, Wt2, 512, 256);

    // ---- Layer 1: 128 -> 4x128, concat, ELU ----
    {
        dim3 g(512 / 128, (N + 127) / 128);
        mfma_gemm_kernel<float, 128><<<g, 256, 0, stream>>>(x, Wt1, bufA, a_src1, a_dst1, alpha_s, alpha_d, N, 128, 512);
        softmax_kernel<4><<<node_wave_blocks, 256, 0, stream>>>(ptrArr, csr_src, alpha_s, alpha_d, alpha_ws, N);
        aggregate_kernel<4, 128, true><<<node_wave_blocks, 256, 0, stream>>>(ptrArr, csr_src, alpha_ws, bufA, b1, bufB, N);
    }
    // ---- Layer 2: 512 -> 4x64, concat, ELU ----
    {
        dim3 g(256 / 128, (N + 127) / 128);
        mfma_gemm_kernel<unsigned short, 64><<<g, 256, 0, stream>>>(bufB, Wt2, bufA, a_src2, a_dst2, alpha_s, alpha_d, N, 512, 256);
        softmax_kernel<4><<<node_wave_blocks, 256, 0, stream>>>(ptrArr, csr_src, alpha_s, alpha_d, alpha_ws, N);
        aggregate_kernel<4, 64, true><<<node_wave_blocks, 256, 0, stream>>>(ptrArr, csr_src, alpha_ws, bufA, b2, bufB, N);
    }
    // ---- Layer 3: 256 -> 2, heads=1, mean(=identity), no ELU ----
    {
        layer3_gemm_kernel<<<node_wave_blocks, 256, 0, stream>>>(bufB, W3, a_src3, a_dst3, h3, alpha_s, alpha_d, N);
        softmax_kernel<1><<<node_wave_blocks, 256, 0, stream>>>(ptrArr, csr_src, alpha_s, alpha_d, alpha_ws, N);
        aggregate3_kernel<<<node_thr_blocks, 256, 0, stream>>>(ptrArr, csr_src, alpha_ws, h3, b3, (float*)d_out, N);
    }
}

// Round 5
// 565.745 us; speedup vs baseline: 2.3280x; 1.0047x over previous
//
#include <hip/hip_runtime.h>
#include <hip/hip_bf16.h>
#include <math.h>

// ---------------------------------------------------------------------------
// GAT (3x GATConv, PyG-style) on MI355X. Round 5: layer-1 restructured as
// aggregate-then-project (gather 256B x-rows from a 26MB L3-resident source
// instead of 1KB h-rows from 102MB), alpha logits via projected attention
// vectors (exact fp32), head-block-diagonal MFMA GEMM with bias+ELU epilogue.
// ---------------------------------------------------------------------------

#define LEAKY_SLOPE 0.2f

typedef __attribute__((ext_vector_type(8))) short bf16x8;
typedef __attribute__((ext_vector_type(4))) float f32x4;
typedef __attribute__((ext_vector_type(4))) float fx4;

__device__ __forceinline__ unsigned short f2bf(float f) {
    unsigned int x = __float_as_uint(f);
    x += 0x7fffu + ((x >> 16) & 1u);   // RNE
    return (unsigned short)(x >> 16);
}
__device__ __forceinline__ float bf2f(unsigned short u) {
    return __uint_as_float(((unsigned int)u) << 16);
}

__device__ __forceinline__ int edge_val(const int* __restrict__ ei, int is64, long long idx) {
    return is64 ? ei[2 * idx] : ei[idx];
}

__global__ void detect_kernel(const unsigned int* __restrict__ ei, int* __restrict__ flag) {
    int lane = threadIdx.x;
    unsigned int v = ei[2 * lane + 1];
    unsigned long long b = __ballot(v != 0u);
    if (lane == 0) *flag = (b == 0ull) ? 1 : 0;
}

__global__ __launch_bounds__(256) void zero2_kernel(int* __restrict__ a, int* __restrict__ b, int n) {
    int i = blockIdx.x * blockDim.x + threadIdx.x;
    if (i < n) { a[i] = 0; b[i] = 0; }
}

__global__ __launch_bounds__(256) void sentinel_kernel(float* __restrict__ out, int n, float v) {
    int i = blockIdx.x * blockDim.x + threadIdx.x;
    if (i < n) out[i] = v;
}

__global__ __launch_bounds__(256) void count_kernel(const int* __restrict__ ei,
                                                    const int* __restrict__ flag,
                                                    int E, int N, int* __restrict__ counts) {
    int e = blockIdx.x * blockDim.x + threadIdx.x;
    if (e >= E + N) return;
    int is64 = *flag;
    int d = (e < E) ? edge_val(ei, is64, (long long)E + e) : (e - E);
    atomicAdd(&counts[d], 1);
}

__global__ __launch_bounds__(256) void scan_block_kernel(const int* __restrict__ counts,
                                                         int* __restrict__ ptrArr,
                                                         int* __restrict__ bsums, int N) {
    __shared__ int sh[256];
    int t = threadIdx.x, i = blockIdx.x * 256 + t;
    int v = (i < N) ? counts[i] : 0;
    sh[t] = v;
    __syncthreads();
    for (int off = 1; off < 256; off <<= 1) {
        int u = (t >= off) ? sh[t - off] : 0;
        __syncthreads();
        sh[t] += u;
        __syncthreads();
    }
    if (i < N) ptrArr[i] = sh[t] - v;
    if (t == 255) bsums[blockIdx.x] = sh[255];
}

__global__ __launch_bounds__(1024) void scan_tops_kernel(const int* __restrict__ bsums,
                                                         int* __restrict__ boff, int nb,
                                                         int* __restrict__ totalOut) {
    __shared__ int sh[1024];
    int t = threadIdx.x;
    int v = (t < nb) ? bsums[t] : 0;
    sh[t] = v;
    __syncthreads();
    for (int off = 1; off < 1024; off <<= 1) {
        int u = (t >= off) ? sh[t - off] : 0;
        __syncthreads();
        sh[t] += u;
        __syncthreads();
    }
    if (t < nb) boff[t] = sh[t] - v;
    if (t == 1023) *totalOut = sh[1023];
}

__global__ __launch_bounds__(256) void scan_add_kernel(int* __restrict__ ptrArr,
                                                       const int* __restrict__ boff, int N) {
    int i = blockIdx.x * blockDim.x + threadIdx.x;
    if (i < N) ptrArr[i] += boff[i >> 8];
}

__global__ __launch_bounds__(256) void fill_kernel(const int* __restrict__ ei,
                                                   const int* __restrict__ flag,
                                                   int E, int N,
                                                   const int* __restrict__ ptrArr,
                                                   int* __restrict__ cursor,
                                                   int* __restrict__ csr_src) {
    int e = blockIdx.x * blockDim.x + threadIdx.x;
    if (e >= E + N) return;
    int is64 = *flag;
    int s, d;
    if (e < E) {
        s = edge_val(ei, is64, e);
        d = edge_val(ei, is64, (long long)E + e);
    } else {
        s = d = e - E;
    }
    int slot = atomicAdd(&cursor[d], 1);
    csr_src[ptrArr[d] + slot] = s;
}

// ---- W [K][N] fp32 -> Wt [N][K] bf16 ----
__global__ __launch_bounds__(256) void transpose_w_kernel(const float* __restrict__ W,
                                                          unsigned short* __restrict__ Wt,
                                                          int K, int Nn) {
    int i = blockIdx.x * blockDim.x + threadIdx.x;
    if (i >= K * Nn) return;
    int n = i / K, k = i - n * K;
    Wt[i] = f2bf(W[(size_t)k * Nn + n]);
}

// ---- x fp32 -> bf16 (vectorized) ----
__global__ __launch_bounds__(256) void convert_x_kernel(const float* __restrict__ x,
                                                        unsigned short* __restrict__ xbf,
                                                        long long total) {
    long long i = (long long)(blockIdx.x * blockDim.x + threadIdx.x) * 4;
    if (i >= total) return;
    fx4 v = *(const fx4*)(x + i);
    alignas(8) unsigned short o[4] = {f2bf(v[0]), f2bf(v[1]), f2bf(v[2]), f2bf(v[3])};
    *(uint2*)(xbf + i) = *(uint2*)o;
}

// ---- ws1[k][h] = sum_c W1[k][h*128+c]*a_src1[h][c]; wd1 same with a_dst1 ----
__global__ __launch_bounds__(256) void proj_attn_kernel(const float* __restrict__ W1,
                                                        const float* __restrict__ a_s,
                                                        const float* __restrict__ a_d,
                                                        float* __restrict__ ws1,
                                                        float* __restrict__ wd1) {
    int t = blockIdx.x * blockDim.x + threadIdx.x;  // 1024 threads: k*8 + sd*4 + h
    if (t >= 1024) return;
    int k = t >> 3, sd = (t >> 2) & 1, h = t & 3;
    const float* a = sd ? a_d : a_s;
    float s = 0.f;
    const float* wr = W1 + (size_t)k * 512 + h * 128;
    const float* ar = a + h * 128;
    for (int c = 0; c < 128; ++c) s += wr[c] * ar[c];
    (sd ? wd1 : ws1)[k * 4 + h] = s;
}

// ---- L1 alpha logits: alpha_s[n][h] = sum_k x[n][k]*ws1[k][h] (fp32 exact) ----
__global__ __launch_bounds__(256) void alpha_x_kernel(const float* __restrict__ x,
                                                      const float* __restrict__ ws1,
                                                      const float* __restrict__ wd1,
                                                      float* __restrict__ out_s,
                                                      float* __restrict__ out_d, int N) {
    int lane = threadIdx.x & 63;
    int wid = threadIdx.x >> 6;
    int n = blockIdx.x * (blockDim.x >> 6) + wid;
    if (n >= N) return;
    int k0 = lane * 2;
    float2 xv = *(const float2*)(x + (size_t)n * 128 + k0);
    fx4 s0 = *(const fx4*)(ws1 + k0 * 4);
    fx4 s1 = *(const fx4*)(ws1 + k0 * 4 + 4);
    fx4 d0 = *(const fx4*)(wd1 + k0 * 4);
    fx4 d1 = *(const fx4*)(wd1 + k0 * 4 + 4);
    float ps[4], pd[4];
#pragma unroll
    for (int h = 0; h < 4; ++h) {
        ps[h] = xv.x * s0[h] + xv.y * s1[h];
        pd[h] = xv.x * d0[h] + xv.y * d1[h];
    }
#pragma unroll
    for (int off = 32; off; off >>= 1)
#pragma unroll
        for (int h = 0; h < 4; ++h) {
            ps[h] += __shfl_xor(ps[h], off);
            pd[h] += __shfl_xor(pd[h], off);
        }
    if (lane == 0) {
        fx4 rs = {ps[0], ps[1], ps[2], ps[3]};
        fx4 rd = {pd[0], pd[1], pd[2], pd[3]};
        *(fx4*)(out_s + (size_t)n * 4) = rs;
        *(fx4*)(out_d + (size_t)n * 4) = rd;
    }
}

// ---------------------------------------------------------------------------
// aggX[n][h*128+k] = sum_e alpha[e][h] * xbf[src_e][k]. Wave per node,
// lane owns k=lane*2..+1 (dword row loads), 4 head accumulators.
// ---------------------------------------------------------------------------
__global__ __launch_bounds__(256) void aggx_kernel(const int* __restrict__ ptrArr,
                                                   const int* __restrict__ csr_src,
                                                   const float* __restrict__ alpha_ws,
                                                   const unsigned short* __restrict__ xbf,
                                                   unsigned short* __restrict__ aggX, int N) {
    int lane = threadIdx.x & 63;
    int wid = threadIdx.x >> 6;
    int n = blockIdx.x * (blockDim.x >> 6) + wid;
    if (n >= N) return;
    int beg = ptrArr[n], end = ptrArr[n + 1];
    float acc[4][2];
#pragma unroll
    for (int h = 0; h < 4; ++h) { acc[h][0] = 0.f; acc[h][1] = 0.f; }
    for (int i = beg; i < end; i += 4) {
        int e1 = (i + 1 < end) ? i + 1 : i;
        int e2 = (i + 2 < end) ? i + 2 : i;
        int e3 = (i + 3 < end) ? i + 3 : i;
        int s0 = csr_src[i], s1 = csr_src[e1], s2 = csr_src[e2], s3 = csr_src[e3];
        fx4 a0 = *(const fx4*)(alpha_ws + (size_t)i * 4);
        fx4 a1 = *(const fx4*)(alpha_ws + (size_t)e1 * 4);
        fx4 a2 = *(const fx4*)(alpha_ws + (size_t)e2 * 4);
        fx4 a3 = *(const fx4*)(alpha_ws + (size_t)e3 * 4);
        if (i + 1 >= end) a1 = (fx4){0.f, 0.f, 0.f, 0.f};
        if (i + 2 >= end) a2 = (fx4){0.f, 0.f, 0.f, 0.f};
        if (i + 3 >= end) a3 = (fx4){0.f, 0.f, 0.f, 0.f};
        unsigned int r0 = *(const unsigned int*)(xbf + (size_t)s0 * 128 + lane * 2);
        unsigned int r1 = *(const unsigned int*)(xbf + (size_t)s1 * 128 + lane * 2);
        unsigned int r2 = *(const unsigned int*)(xbf + (size_t)s2 * 128 + lane * 2);
        unsigned int r3 = *(const unsigned int*)(xbf + (size_t)s3 * 128 + lane * 2);
        float x00 = bf2f((unsigned short)r0), x01 = bf2f((unsigned short)(r0 >> 16));
        float x10 = bf2f((unsigned short)r1), x11 = bf2f((unsigned short)(r1 >> 16));
        float x20 = bf2f((unsigned short)r2), x21 = bf2f((unsigned short)(r2 >> 16));
        float x30 = bf2f((unsigned short)r3), x31 = bf2f((unsigned short)(r3 >> 16));
#pragma unroll
        for (int h = 0; h < 4; ++h) {
            acc[h][0] += a0[h] * x00 + a1[h] * x10 + a2[h] * x20 + a3[h] * x30;
            acc[h][1] += a0[h] * x01 + a1[h] * x11 + a2[h] * x21 + a3[h] * x31;
        }
    }
#pragma unroll
    for (int h = 0; h < 4; ++h) {
        alignas(4) unsigned short o[2] = {f2bf(acc[h][0]), f2bf(acc[h][1])};
        *(unsigned int*)(aggX + (size_t)n * 512 + h * 128 + lane * 2) = *(unsigned int*)o;
    }
}

// ---------------------------------------------------------------------------
// MFMA bf16 GEMM: C[M,*] = A[M,K(+off)] @ Bt[N,K]^T. BM=BN=128, BK=64, 4 waves.
// HEAD_DIAG: A k-window starts at bn*128 (head-block-diagonal, lda=LDA).
// BIAS_ELU: epilogue x = ELU(acc + bias[col]). C_HEAD>0: fused alpha epilogue.
// ---------------------------------------------------------------------------
template <int C_HEAD, bool BIAS_ELU, bool HEAD_DIAG>
__global__ __launch_bounds__(256) void mfma_gemm_kernel(const unsigned short* __restrict__ A,
                                                        int lda,
                                                        const unsigned short* __restrict__ Bt,
                                                        unsigned short* __restrict__ C,
                                                        const float* __restrict__ a_src,
                                                        const float* __restrict__ a_dst,
                                                        float* __restrict__ alpha_s,
                                                        float* __restrict__ alpha_d,
                                                        const float* __restrict__ bias,
                                                        int M, int K, int N) {
    __shared__ unsigned short As[128 * 64];
    __shared__ unsigned short Bs[128 * 64];
    const int bm = blockIdx.y, bn = blockIdx.x;
    const int tid = threadIdx.x;
    const int lane = tid & 63, wid = tid >> 6;
    const int wr = wid >> 1, wc = wid & 1;
    const int l15 = lane & 15, l4 = lane >> 4;
    const int a_off = HEAD_DIAG ? bn * 128 : 0;
    f32x4 acc[4][4];
#pragma unroll
    for (int m = 0; m < 4; ++m)
#pragma unroll
        for (int n = 0; n < 4; ++n) acc[m][n] = (f32x4){0.f, 0.f, 0.f, 0.f};

    for (int k0 = 0; k0 < K; k0 += 64) {
#pragma unroll
        for (int it = 0; it < 4; ++it) {
            int idx = it * 256 + tid;
            int row = idx >> 3, ch = idx & 7;
            int grow = bm * 128 + row;
            int4 v = {0, 0, 0, 0};
            if (grow < M) v = *(const int4*)(A + (size_t)grow * lda + a_off + k0 + ch * 8);
            int dst = row * 128 + ((ch * 16) ^ ((row & 7) << 4));
            *(int4*)((char*)As + dst) = v;
        }
#pragma unroll
        for (int it = 0; it < 4; ++it) {
            int idx = it * 256 + tid;
            int row = idx >> 3, ch = idx & 7;
            int4 v = *(const int4*)(Bt + (size_t)(bn * 128 + row) * K + k0 + ch * 8);
            int dst = row * 128 + ((ch * 16) ^ ((row & 7) << 4));
            *(int4*)((char*)Bs + dst) = v;
        }
        __syncthreads();
#pragma unroll
        for (int step = 0; step < 2; ++step) {
            bf16x8 af[4], bfr[4];
            int kb = step * 64 + l4 * 16;
#pragma unroll
            for (int m = 0; m < 4; ++m) {
                int r = wr * 64 + m * 16 + l15;
                af[m] = *(const bf16x8*)((const char*)As + r * 128 + (kb ^ ((r & 7) << 4)));
            }
#pragma unroll
            for (int n = 0; n < 4; ++n) {
                int r = wc * 64 + n * 16 + l15;
                bfr[n] = *(const bf16x8*)((const char*)Bs + r * 128 + (kb ^ ((r & 7) << 4)));
            }
#pragma unroll
            for (int m = 0; m < 4; ++m)
#pragma unroll
                for (int n = 0; n < 4; ++n)
                    acc[m][n] = __builtin_amdgcn_mfma_f32_16x16x32_bf16(af[m], bfr[n], acc[m][n], 0, 0, 0);
        }
        __syncthreads();
    }
    // ---- C store: C/D layout col=lane&15, row=(lane>>4)*4+reg ----
#pragma unroll
    for (int m = 0; m < 4; ++m)
#pragma unroll
        for (int j = 0; j < 4; ++j) {
            int row = bm * 128 + wr * 64 + m * 16 + l4 * 4 + j;
            if (row < M) {
#pragma unroll
                for (int n = 0; n < 4; ++n) {
                    int col = bn * 128 + wc * 64 + n * 16 + l15;
                    float v = acc[m][n][j];
                    if (BIAS_ELU) {
                        v += bias[col];
                        v = (v > 0.f) ? v : expm1f(v);
                    }
                    C[(size_t)row * N + col] = f2bf(v);
                }
            }
        }
    // ---- fused alpha epilogue ----
    if constexpr (C_HEAD > 0) {
        const int H = N / C_HEAD;
        float ps[4][4], pd[4][4];
#pragma unroll
        for (int m = 0; m < 4; ++m)
#pragma unroll
            for (int j = 0; j < 4; ++j) { ps[m][j] = 0.f; pd[m][j] = 0.f; }
#pragma unroll
        for (int n = 0; n < 4; ++n) {
            int col = bn * 128 + wc * 64 + n * 16 + l15;
            float asv = a_src[col];
            float adv = a_dst[col];
#pragma unroll
            for (int m = 0; m < 4; ++m)
#pragma unroll
                for (int j = 0; j < 4; ++j) {
                    ps[m][j] += acc[m][n][j] * asv;
                    pd[m][j] += acc[m][n][j] * adv;
                }
        }
#pragma unroll
        for (int off = 1; off < 16; off <<= 1)
#pragma unroll
            for (int m = 0; m < 4; ++m)
#pragma unroll
                for (int j = 0; j < 4; ++j) {
                    ps[m][j] += __shfl_xor(ps[m][j], off);
                    pd[m][j] += __shfl_xor(pd[m][j], off);
                }
        if constexpr (C_HEAD == 64) {
            if (l15 == 0) {
                int head = bn * 2 + wc;
#pragma unroll
                for (int m = 0; m < 4; ++m)
#pragma unroll
                    for (int j = 0; j < 4; ++j) {
                        int row = bm * 128 + wr * 64 + m * 16 + l4 * 4 + j;
                        if (row < M) {
                            alpha_s[(size_t)row * H + head] = ps[m][j];
                            alpha_d[(size_t)row * H + head] = pd[m][j];
                        }
                    }
            }
        } else {
            float* red = (float*)As;
            if (l15 == 0) {
#pragma unroll
                for (int m = 0; m < 4; ++m)
#pragma unroll
                    for (int j = 0; j < 4; ++j) {
                        int rl = wr * 64 + m * 16 + l4 * 4 + j;
                        red[(wc * 2 + 0) * 128 + rl] = ps[m][j];
                        red[(wc * 2 + 1) * 128 + rl] = pd[m][j];
                    }
            }
            __syncthreads();
            if (wc == 0 && l15 == 0) {
#pragma unroll
                for (int m = 0; m < 4; ++m)
#pragma unroll
                    for (int j = 0; j < 4; ++j) {
                        int rl = wr * 64 + m * 16 + l4 * 4 + j;
                        int row = bm * 128 + rl;
                        if (row < M) {
                            alpha_s[(size_t)row * H + bn] = red[0 * 128 + rl] + red[2 * 128 + rl];
                            alpha_d[(size_t)row * H + bn] = red[1 * 128 + rl] + red[3 * 128 + rl];
                        }
                    }
            }
        }
    }
}

// ---------------------------------------------------------------------------
// Segment softmax per dst node. Fast path deg<=64: one lane per edge.
// ---------------------------------------------------------------------------
template <int H>
__global__ __launch_bounds__(256) void softmax_kernel(const int* __restrict__ ptrArr,
                                                      const int* __restrict__ csr_src,
                                                      const float* __restrict__ as,
                                                      const float* __restrict__ ad,
                                                      float* __restrict__ alpha_ws, int N) {
    int lane = threadIdx.x & 63;
    int wid = threadIdx.x >> 6;
    int n = blockIdx.x * (blockDim.x >> 6) + wid;
    if (n >= N) return;
    int beg = ptrArr[n], end = ptrArr[n + 1];
    int deg = end - beg;
    if (deg <= 64) {
        bool act = lane < deg;
        int i = beg + (act ? lane : 0);
        int s = csr_src[i];
        float e[H];
        if constexpr (H == 4) {
            fx4 av = *(const fx4*)(as + (size_t)s * 4);
            fx4 dv = *(const fx4*)(ad + (size_t)n * 4);
#pragma unroll
            for (int hh = 0; hh < 4; ++hh) {
                float x = av[hh] + dv[hh];
                x = (x >= 0.f) ? x : LEAKY_SLOPE * x;
                e[hh] = act ? x : -INFINITY;
            }
        } else {
            float x = as[s] + ad[n];
            x = (x >= 0.f) ? x : LEAKY_SLOPE * x;
            e[0] = act ? x : -INFINITY;
        }
#pragma unroll
        for (int hh = 0; hh < H; ++hh) {
            float mm = e[hh];
#pragma unroll
            for (int off = 32; off; off >>= 1) mm = fmaxf(mm, __shfl_xor(mm, off));
            float ex = expf(e[hh] - mm);
            float ss = ex;
#pragma unroll
            for (int off = 32; off; off >>= 1) ss += __shfl_xor(ss, off);
            e[hh] = ex / (ss + 1e-16f);
        }
        if (act) {
            if constexpr (H == 4) {
                fx4 r = {e[0], e[1], e[2], e[3]};
                *(fx4*)(alpha_ws + (size_t)i * 4) = r;
            } else {
                alpha_ws[i] = e[0];
            }
        }
    } else {
#pragma unroll
        for (int hh = 0; hh < H; ++hh) {
            float advv = ad[(size_t)n * H + hh];
            float m = -INFINITY;
            for (int i = beg + lane; i < end; i += 64) {
                int s = csr_src[i];
                float v = as[(size_t)s * H + hh] + advv;
                v = (v >= 0.f) ? v : LEAKY_SLOPE * v;
                m = fmaxf(m, v);
            }
#pragma unroll
            for (int off = 32; off; off >>= 1) m = fmaxf(m, __shfl_xor(m, off));
            float ssum = 0.f;
            for (int i = beg + lane; i < end; i += 64) {
                int s = csr_src[i];
                float v = as[(size_t)s * H + hh] + advv;
                v = (v >= 0.f) ? v : LEAKY_SLOPE * v;
                ssum += expf(v - m);
            }
#pragma unroll
            for (int off = 32; off; off >>= 1) ssum += __shfl_xor(ssum, off);
            float inv = 1.f / (ssum + 1e-16f);
            for (int i = beg + lane; i < end; i += 64) {
                int s = csr_src[i];
                float v = as[(size_t)s * H + hh] + advv;
                v = (v >= 0.f) ? v : LEAKY_SLOPE * v;
                alpha_ws[(size_t)i * H + hh] = expf(v - m) * inv;
            }
        }
    }
}

// ---------------------------------------------------------------------------
// Aggregate (layer 2): out[n,:] = sum alpha_e * h[src_e,:] + b (+ELU).
// ---------------------------------------------------------------------------
template <int H, int C, bool DO_ELU>
__global__ __launch_bounds__(256) void aggregate_kernel(const int* __restrict__ ptrArr,
                                                        const int* __restrict__ csr_src,
                                                        const float* __restrict__ alpha_ws,
                                                        const unsigned short* __restrict__ hmat,
                                                        const float* __restrict__ bias,
                                                        unsigned short* __restrict__ out, int N) {
    constexpr int F = H * C;
    constexpr int VPL = F / 64;
    int lane = threadIdx.x & 63;
    int wid = threadIdx.x >> 6;
    int n = blockIdx.x * (blockDim.x >> 6) + wid;
    if (n >= N) return;
    int beg = ptrArr[n], end = ptrArr[n + 1];
    int head = (lane * VPL) / C;
    float acc[VPL];
#pragma unroll
    for (int t = 0; t < VPL; ++t) acc[t] = 0.f;
    for (int i = beg; i < end; i += 4) {
        int e1 = (i + 1 < end) ? i + 1 : i;
        int e2 = (i + 2 < end) ? i + 2 : i;
        int e3 = (i + 3 < end) ? i + 3 : i;
        int s0 = csr_src[i], s1 = csr_src[e1], s2 = csr_src[e2], s3 = csr_src[e3];
        float al0 = alpha_ws[(size_t)i * H + head];
        float al1 = (i + 1 < end) ? alpha_ws[(size_t)e1 * H + head] : 0.f;
        float al2 = (i + 2 < end) ? alpha_ws[(size_t)e2 * H + head] : 0.f;
        float al3 = (i + 3 < end) ? alpha_ws[(size_t)e3 * H + head] : 0.f;
        const unsigned short* p0 = hmat + (size_t)s0 * F + lane * VPL;
        const unsigned short* p1 = hmat + (size_t)s1 * F + lane * VPL;
        const unsigned short* p2 = hmat + (size_t)s2 * F + lane * VPL;
        const unsigned short* p3 = hmat + (size_t)s3 * F + lane * VPL;
        alignas(16) unsigned short v0[VPL], v1[VPL], v2[VPL], v3[VPL];
        if constexpr (VPL == 8) {
            *(int4*)v0 = *(const int4*)p0;
            *(int4*)v1 = *(const int4*)p1;
            *(int4*)v2 = *(const int4*)p2;
            *(int4*)v3 = *(const int4*)p3;
        } else {
            *(uint2*)v0 = *(const uint2*)p0;
            *(uint2*)v1 = *(const uint2*)p1;
            *(uint2*)v2 = *(const uint2*)p2;
            *(uint2*)v3 = *(const uint2*)p3;
        }
#pragma unroll
        for (int t = 0; t < VPL; ++t)
            acc[t] += al0 * bf2f(v0[t]) + al1 * bf2f(v1[t]) + al2 * bf2f(v2[t]) + al3 * bf2f(v3[t]);
    }
    alignas(16) unsigned short o[VPL];
#pragma unroll
    for (int t = 0; t < VPL; ++t) {
        float x = acc[t] + bias[lane * VPL + t];
        if (DO_ELU) x = (x > 0.f) ? x : expm1f(x);
        o[t] = f2bf(x);
    }
    unsigned short* op = out + (size_t)n * F + lane * VPL;
    if constexpr (VPL == 8) *(int4*)op = *(int4*)o;
    else *(uint2*)op = *(uint2*)o;
}

// ---------------------------------------------------------------------------
// Layer 3: h3 = x3 @ W3 (K=256, 2 cols) fused with alpha dots. One wave/node.
// ---------------------------------------------------------------------------
__global__ __launch_bounds__(256) void layer3_gemm_kernel(const unsigned short* __restrict__ x,
                                                          const float* __restrict__ W,
                                                          const float* __restrict__ a_s,
                                                          const float* __restrict__ a_d,
                                                          float* __restrict__ h3,
                                                          float* __restrict__ out_s,
                                                          float* __restrict__ out_d, int N) {
    int lane = threadIdx.x & 63;
    int wid = threadIdx.x >> 6;
    int n = blockIdx.x * (blockDim.x >> 6) + wid;
    if (n >= N) return;
    const unsigned short* xr = x + (size_t)n * 256 + lane * 4;
    alignas(8) unsigned short v[4];
    *(uint2*)v = *(const uint2*)xr;
    int k0 = lane * 4;
    fx4 w0 = *(const fx4*)(W + k0 * 2);
    fx4 w1 = *(const fx4*)(W + k0 * 2 + 4);
    float a0 = bf2f(v[0]) * w0[0] + bf2f(v[1]) * w0[2] + bf2f(v[2]) * w1[0] + bf2f(v[3]) * w1[2];
    float a1 = bf2f(v[0]) * w0[1] + bf2f(v[1]) * w0[3] + bf2f(v[2]) * w1[1] + bf2f(v[3]) * w1[3];
#pragma unroll
    for (int off = 32; off; off >>= 1) {
        a0 += __shfl_xor(a0, off);
        a1 += __shfl_xor(a1, off);
    }
    if (lane == 0) {
        h3[(size_t)n * 2 + 0] = a0;
        h3[(size_t)n * 2 + 1] = a1;
        out_s[n] = a0 * a_s[0] + a1 * a_s[1];
        out_d[n] = a0 * a_d[0] + a1 * a_d[1];
    }
}

__global__ __launch_bounds__(256) void aggregate3_kernel(const int* __restrict__ ptrArr,
                                                         const int* __restrict__ csr_src,
                                                         const float* __restrict__ alpha_ws,
                                                         const float* __restrict__ h3,
                                                         const float* __restrict__ b3,
                                                         float* __restrict__ out, int N) {
    int n = blockIdx.x * blockDim.x + threadIdx.x;
    if (n >= N) return;
    float a0 = 0.f, a1 = 0.f;
    int beg = ptrArr[n], end = ptrArr[n + 1];
    for (int i = beg; i < end; ++i) {
        int s = csr_src[i];
        float al = alpha_ws[i];
        a0 += al * h3[(size_t)s * 2 + 0];
        a1 += al * h3[(size_t)s * 2 + 1];
    }
    out[(size_t)n * 2 + 0] = a0 + b3[0];
    out[(size_t)n * 2 + 1] = a1 + b3[1];
}

// ---------------------------------------------------------------------------

extern "C" void kernel_launch(void* const* d_in, const int* in_sizes, int n_in,
                              void* d_out, int out_size, void* d_ws, size_t ws_size,
                              hipStream_t stream) {
    const float* x      = (const float*)d_in[0];
    const int*   ei     = (const int*)d_in[1];
    const float* W1     = (const float*)d_in[2];
    const float* a_src1 = (const float*)d_in[3];
    const float* a_dst1 = (const float*)d_in[4];
    const float* b1     = (const float*)d_in[5];
    const float* W2     = (const float*)d_in[6];
    const float* a_src2 = (const float*)d_in[7];
    const float* a_dst2 = (const float*)d_in[8];
    const float* b2     = (const float*)d_in[9];
    const float* W3     = (const float*)d_in[10];
    const float* a_src3 = (const float*)d_in[11];
    const float* a_dst3 = (const float*)d_in[12];
    const float* b3     = (const float*)d_in[13];

    const int N = in_sizes[0] / 128;
    const int E = in_sizes[1] / 2;
    const int ET = E + N;
    const int nb = (N + 255) / 256;

    size_t need = 0;
    auto carve = [&](size_t bytes) -> size_t {
        size_t off = need;
        need += (bytes + 255) & ~(size_t)255;
        return off;
    };
    size_t o_counts   = carve((size_t)N * 4);
    size_t o_cursor   = carve((size_t)N * 4);
    size_t o_ptr      = carve((size_t)(N + 1) * 4);
    size_t o_csr      = carve((size_t)ET * 4);
    size_t o_flag     = carve(4);
    size_t o_bsums    = carve((size_t)2048 * 4);
    size_t o_boff     = carve((size_t)2048 * 4);
    size_t o_alpha_s  = carve((size_t)N * 4 * 4);
    size_t o_alpha_d  = carve((size_t)N * 4 * 4);
    size_t o_alpha_ws = carve((size_t)ET * 4 * 4);
    size_t o_h3       = carve((size_t)N * 2 * 4);
    size_t o_wsd      = carve((size_t)128 * 4 * 4 * 2);  // ws1 + wd1
    size_t o_wt1      = carve((size_t)512 * 128 * 2);
    size_t o_wt2      = carve((size_t)256 * 512 * 2);
    size_t o_xbf      = carve((size_t)N * 128 * 2);
    size_t o_bufA     = carve((size_t)N * 512 * 2);
    size_t o_bufB     = carve((size_t)N * 512 * 2);

    if (need > ws_size) {
        sentinel_kernel<<<(out_size + 255) / 256, 256, 0, stream>>>(
            (float*)d_out, out_size, (float)(ws_size >> 20));
        return;
    }

    char* w = (char*)d_ws;
    int*   counts   = (int*)(w + o_counts);
    int*   cursor   = (int*)(w + o_cursor);
    int*   ptrArr   = (int*)(w + o_ptr);
    int*   csr_src  = (int*)(w + o_csr);
    int*   flag     = (int*)(w + o_flag);
    int*   bsums    = (int*)(w + o_bsums);
    int*   boff     = (int*)(w + o_boff);
    float* alpha_s  = (float*)(w + o_alpha_s);
    float* alpha_d  = (float*)(w + o_alpha_d);
    float* alpha_ws = (float*)(w + o_alpha_ws);
    float* h3       = (float*)(w + o_h3);
    float* ws1      = (float*)(w + o_wsd);
    float* wd1      = ws1 + 128 * 4;
    unsigned short* Wt1  = (unsigned short*)(w + o_wt1);
    unsigned short* Wt2  = (unsigned short*)(w + o_wt2);
    unsigned short* xbf  = (unsigned short*)(w + o_xbf);
    unsigned short* bufA = (unsigned short*)(w + o_bufA);
    unsigned short* bufB = (unsigned short*)(w + o_bufB);

    const int edge_blocks = (ET + 255) / 256;
    const int node_wave_blocks = (N + 3) / 4;
    const int node_thr_blocks = (N + 255) / 256;

    // ---- CSR build ----
    zero2_kernel<<<node_thr_blocks, 256, 0, stream>>>(counts, cursor, N);
    detect_kernel<<<1, 64, 0, stream>>>((const unsigned int*)ei, flag);
    count_kernel<<<edge_blocks, 256, 0, stream>>>(ei, flag, E, N, counts);
    scan_block_kernel<<<nb, 256, 0, stream>>>(counts, ptrArr, bsums, N);
    scan_tops_kernel<<<1, 1024, 0, stream>>>(bsums, boff, nb, ptrArr + N);
    scan_add_kernel<<<node_thr_blocks, 256, 0, stream>>>(ptrArr, boff, N);
    fill_kernel<<<edge_blocks, 256, 0, stream>>>(ei, flag, E, N, ptrArr, cursor, csr_src);

    // ---- precomputes ----
    transpose_w_kernel<<<(512 * 128 + 255) / 256, 256, 0, stream>>>(W1, Wt1, 128, 512);
    transpose_w_kernel<<<(256 * 512 + 255) / 256, 256, 0, stream>>>(W2, Wt2, 512, 256);
    convert_x_kernel<<<(int)(((size_t)N * 128 / 4 + 255) / 256), 256, 0, stream>>>(x, xbf, (long long)N * 128);
    proj_attn_kernel<<<4, 256, 0, stream>>>(W1, a_src1, a_dst1, ws1, wd1);

    // ---- Layer 1 (aggregate-then-project): 128 -> 4x128, concat, ELU ----
    {
        alpha_x_kernel<<<node_wave_blocks, 256, 0, stream>>>(x, ws1, wd1, alpha_s, alpha_d, N);
        softmax_kernel<4><<<node_wave_blocks, 256, 0, stream>>>(ptrArr, csr_src, alpha_s, alpha_d, alpha_ws, N);
        aggx_kernel<<<node_wave_blocks, 256, 0, stream>>>(ptrArr, csr_src, alpha_ws, xbf, bufA, N);
        dim3 g(4, (N + 127) / 128);  // bn = head (block-diagonal)
        mfma_gemm_kernel<0, true, true><<<g, 256, 0, stream>>>(bufA, 512, Wt1, bufB,
            nullptr, nullptr, nullptr, nullptr, b1, N, 128, 512);
    }
    // ---- Layer 2: 512 -> 4x64, concat, ELU ----
    {
        dim3 g(256 / 128, (N + 127) / 128);
        mfma_gemm_kernel<64, false, false><<<g, 256, 0, stream>>>(bufB, 512, Wt2, bufA,
            a_src2, a_dst2, alpha_s, alpha_d, nullptr, N, 512, 256);
        softmax_kernel<4><<<node_wave_blocks, 256, 0, stream>>>(ptrArr, csr_src, alpha_s, alpha_d, alpha_ws, N);
        aggregate_kernel<4, 64, true><<<node_wave_blocks, 256, 0, stream>>>(ptrArr, csr_src, alpha_ws, bufA, b2, bufB, N);
    }
    // ---- Layer 3: 256 -> 2, heads=1, mean(=identity), no ELU ----
    {
        layer3_gemm_kernel<<<node_wave_blocks, 256, 0, stream>>>(bufB, W3, a_src3, a_dst3, h3, alpha_s, alpha_d, N);
        softmax_kernel<1><<<node_wave_blocks, 256, 0, stream>>>(ptrArr, csr_src, alpha_s, alpha_d, alpha_ws, N);
        aggregate3_kernel<<<node_thr_blocks, 256, 0, stream>>>(ptrArr, csr_src, alpha_ws, h3, b3, (float*)d_out, N);
    }
}